// Round 1
// baseline (501.994 us; speedup 1.0000x reference)
//
#include <hip/hip_runtime.h>
#include <hip/hip_bf16.h>

constexpr int N_NODES = 40000;
constexpr int N_EDGES = 640000;
constexpr int D = 128;
constexpr float BN_EPS = 1e-5f;

// ---------------------------------------------------------------------------
// Kernel 1: edge scatter. One thread per (edge, feature).
// agg[dst][d] += h[src][d];  deg[dst] += 1 (once per edge, on d==0 lane).
// Consecutive 128 threads share one edge -> src/dst loads are wave-broadcast,
// h row read is coalesced (512B), atomic adds hit one contiguous row.
// ---------------------------------------------------------------------------
__global__ void scatter_kernel(const float* __restrict__ h,
                               const int* __restrict__ src,
                               const int* __restrict__ dst,
                               float* __restrict__ agg,
                               float* __restrict__ deg) {
    unsigned idx = blockIdx.x * blockDim.x + threadIdx.x;
    unsigned total = (unsigned)N_EDGES * D;
    if (idx >= total) return;
    int e = idx >> 7;          // / 128
    int d = idx & 127;
    int s = src[e];
    int t = dst[e];
    atomicAdd(&agg[(size_t)t * D + d], h[(size_t)s * D + d]);
    if (d == 0) atomicAdd(&deg[t], 1.0f);
}

// ---------------------------------------------------------------------------
// Kernel 2: out_pre = relu(h @ W_self + (agg/deg) @ W_neigh + b) * snorm
// One block = 128 threads (thread d owns output feature d), NPB nodes/tile.
// W reads: W[k*128+d] coalesced across the wave, L1/L2 resident (128 KB).
// h/hn rows staged in LDS; hs[i][k] is a wave-broadcast read (conflict-free).
// Also accumulates per-feature sum / sumsq for BN (one atomic pair per block).
// ---------------------------------------------------------------------------
constexpr int NPB = 8;  // nodes per block-tile

__global__ __launch_bounds__(128) void gemm_kernel(
        const float* __restrict__ h,
        const float* __restrict__ snorm,
        const float* __restrict__ Wself,
        const float* __restrict__ Wneigh,
        const float* __restrict__ bias,
        const float* __restrict__ agg,
        const float* __restrict__ deg,
        float* __restrict__ pre,          // d_out used as scratch
        float* __restrict__ sums,
        float* __restrict__ sumsq) {
    __shared__ float hs[NPB][D];
    __shared__ float hn[NPB][D];
    int d = threadIdx.x;

    float lsum = 0.f, lsq = 0.f;
    int ntiles = N_NODES / NPB;  // 5000, exact

    for (int tile = blockIdx.x; tile < ntiles; tile += gridDim.x) {
        int n0 = tile * NPB;
        #pragma unroll
        for (int i = 0; i < NPB; i++) {
            int n = n0 + i;
            hs[i][d] = h[(size_t)n * D + d];
            float rd = 1.0f / fmaxf(deg[n], 1.0f);
            hn[i][d] = agg[(size_t)n * D + d] * rd;
        }
        __syncthreads();

        float acc[NPB];
        #pragma unroll
        for (int i = 0; i < NPB; i++) acc[i] = 0.f;

        for (int k = 0; k < D; k++) {
            float ws = Wself[k * D + d];
            float wn = Wneigh[k * D + d];
            #pragma unroll
            for (int i = 0; i < NPB; i++) {
                acc[i] = fmaf(hs[i][k], ws, acc[i]);
                acc[i] = fmaf(hn[i][k], wn, acc[i]);
            }
        }

        float bb = bias[d];
        #pragma unroll
        for (int i = 0; i < NPB; i++) {
            int n = n0 + i;
            float v = acc[i] + bb;
            v = fmaxf(v, 0.f);
            v *= snorm[n];
            pre[(size_t)n * D + d] = v;
            lsum += v;
            lsq  += v * v;
        }
        __syncthreads();
    }
    atomicAdd(&sums[d], lsum);
    atomicAdd(&sumsq[d], lsq);
}

// ---------------------------------------------------------------------------
// Kernel 3: fold BN statistics into affine scale/bias (128 threads).
// ---------------------------------------------------------------------------
__global__ void stats_kernel(const float* __restrict__ sums,
                             const float* __restrict__ sumsq,
                             const float* __restrict__ gamma,
                             const float* __restrict__ beta,
                             float* __restrict__ scale,
                             float* __restrict__ shift) {
    int d = threadIdx.x;
    float invN = 1.0f / (float)N_NODES;
    float mean = sums[d] * invN;
    float var  = sumsq[d] * invN - mean * mean;
    float sc   = gamma[d] * rsqrtf(var + BN_EPS);
    scale[d] = sc;
    shift[d] = beta[d] - mean * sc;
}

// ---------------------------------------------------------------------------
// Kernel 4: out = h + pre*scale[d] + shift[d]   (in-place on d_out, float4)
// ---------------------------------------------------------------------------
__global__ void final_kernel(const float* __restrict__ h,
                             const float* __restrict__ scale,
                             const float* __restrict__ shift,
                             float* __restrict__ out) {
    int idx = blockIdx.x * blockDim.x + threadIdx.x;  // over N*D/4
    int total = N_NODES * D / 4;
    if (idx >= total) return;
    const float4 hv = reinterpret_cast<const float4*>(h)[idx];
    float4 ov = reinterpret_cast<float4*>(out)[idx];
    int d0 = (idx * 4) & 127;
    ov.x = hv.x + ov.x * scale[d0 + 0] + shift[d0 + 0];
    ov.y = hv.y + ov.y * scale[d0 + 1] + shift[d0 + 1];
    ov.z = hv.z + ov.z * scale[d0 + 2] + shift[d0 + 2];
    ov.w = hv.w + ov.w * scale[d0 + 3] + shift[d0 + 3];
    reinterpret_cast<float4*>(out)[idx] = ov;
}

// ---------------------------------------------------------------------------
extern "C" void kernel_launch(void* const* d_in, const int* in_sizes, int n_in,
                              void* d_out, int out_size, void* d_ws, size_t ws_size,
                              hipStream_t stream) {
    const float* h      = (const float*)d_in[0];
    const float* snorm  = (const float*)d_in[1];
    const float* Wself  = (const float*)d_in[2];
    const float* Wneigh = (const float*)d_in[3];
    const float* bias   = (const float*)d_in[4];
    const float* gamma  = (const float*)d_in[5];
    const float* beta   = (const float*)d_in[6];
    const int*   src    = (const int*)d_in[7];
    const int*   dst    = (const int*)d_in[8];
    float* out = (float*)d_out;

    // workspace layout (floats):
    // [ agg : N*D ][ deg : N ][ sums : D ][ sumsq : D ][ scale : D ][ shift : D ]
    float* ws_f  = (float*)d_ws;
    float* agg   = ws_f;
    float* deg   = agg + (size_t)N_NODES * D;
    float* sums  = deg + N_NODES;
    float* sumsq = sums + D;
    float* scale = sumsq + D;
    float* shift = scale + D;

    // zero the accumulated regions (agg, deg, sums, sumsq)
    size_t zero_bytes = ((size_t)N_NODES * D + N_NODES + 2 * D) * sizeof(float);
    hipMemsetAsync(d_ws, 0, zero_bytes, stream);

    // 1) scatter
    {
        unsigned total = (unsigned)N_EDGES * D;
        int block = 256;
        int grid = (total + block - 1) / block;
        scatter_kernel<<<grid, block, 0, stream>>>(h, src, dst, agg, deg);
    }
    // 2) dual GEMM + relu + snorm + BN partial stats
    {
        int grid = 1024;
        gemm_kernel<<<grid, 128, 0, stream>>>(h, snorm, Wself, Wneigh, bias,
                                              agg, deg, out, sums, sumsq);
    }
    // 3) BN stats -> affine
    stats_kernel<<<1, D, 0, stream>>>(sums, sumsq, gamma, beta, scale, shift);
    // 4) finalize: residual + BN affine
    {
        int total = N_NODES * D / 4;
        int block = 256;
        int grid = (total + block - 1) / block;
        final_kernel<<<grid, block, 0, stream>>>(h, scale, shift, out);
    }
}

// Round 2
// 409.254 us; speedup vs baseline: 1.2266x; 1.2266x over previous
//
#include <hip/hip_runtime.h>
#include <hip/hip_bf16.h>

constexpr int N_NODES = 40000;
constexpr int N_EDGES = 640000;
constexpr int D = 128;
constexpr float BN_EPS = 1e-5f;

// ---------------------------------------------------------------------------
// Kernel 1a: histogram of in-degree (int atomics, 640k ops on 40k counters)
// ---------------------------------------------------------------------------
__global__ void hist_kernel(const int* __restrict__ dst,
                            int* __restrict__ deg_i) {
    int e = blockIdx.x * blockDim.x + threadIdx.x;
    if (e >= N_EDGES) return;
    atomicAdd(&deg_i[dst[e]], 1);
}

// ---------------------------------------------------------------------------
// Kernel 1b: exclusive prefix scan of deg_i -> row_start (single block, 1024t)
// ---------------------------------------------------------------------------
__global__ __launch_bounds__(1024) void scan_kernel(const int* __restrict__ deg_i,
                                                    int* __restrict__ row_start) {
    __shared__ int part[1024];
    const int CH = 40;  // 1024*40 >= 40000
    int t = threadIdx.x;
    int base = t * CH;
    int s = 0;
    for (int i = 0; i < CH; i++) {
        int idx = base + i;
        if (idx < N_NODES) s += deg_i[idx];
    }
    part[t] = s;
    __syncthreads();
    // Hillis-Steele inclusive scan
    for (int off = 1; off < 1024; off <<= 1) {
        int v = (t >= off) ? part[t - off] : 0;
        __syncthreads();
        part[t] += v;
        __syncthreads();
    }
    int run = part[t] - s;  // exclusive prefix of this chunk
    for (int i = 0; i < CH; i++) {
        int idx = base + i;
        if (idx < N_NODES) {
            row_start[idx] = run;
            run += deg_i[idx];
        }
    }
    if (t == 1023) row_start[N_NODES] = part[1023];
}

// ---------------------------------------------------------------------------
// Kernel 1c: bucket-fill sorted src list (CSR column indices)
// ---------------------------------------------------------------------------
__global__ void fill_kernel(const int* __restrict__ src,
                            const int* __restrict__ dst,
                            const int* __restrict__ row_start,
                            int* __restrict__ cursor,
                            int* __restrict__ esrc) {
    int e = blockIdx.x * blockDim.x + threadIdx.x;
    if (e >= N_EDGES) return;
    int t = dst[e];
    int p = atomicAdd(&cursor[t], 1);
    esrc[row_start[t] + p] = src[e];
}

// ---------------------------------------------------------------------------
// Kernel 1d: gather + mean. 32 threads (float4 lanes) per node.
// Writes h_neigh directly into d_out; gemm_kernel reads it tile-locally
// before overwriting the same rows (one block owns each node -> safe).
// ---------------------------------------------------------------------------
__global__ void gather_kernel(const float4* __restrict__ h4,
                              const int* __restrict__ row_start,
                              const int* __restrict__ esrc,
                              float4* __restrict__ hn4) {
    int gid = blockIdx.x * blockDim.x + threadIdx.x;
    int node = gid >> 5;
    int d4 = gid & 31;
    if (node >= N_NODES) return;
    int s0 = row_start[node];
    int s1 = row_start[node + 1];
    float4 acc = make_float4(0.f, 0.f, 0.f, 0.f);
    int j = s0;
    for (; j + 1 < s1; j += 2) {
        int a = esrc[j];
        int b = esrc[j + 1];
        float4 va = h4[(size_t)a * 32 + d4];
        float4 vb = h4[(size_t)b * 32 + d4];
        acc.x += va.x; acc.y += va.y; acc.z += va.z; acc.w += va.w;
        acc.x += vb.x; acc.y += vb.y; acc.z += vb.z; acc.w += vb.w;
    }
    if (j < s1) {
        int a = esrc[j];
        float4 va = h4[(size_t)a * 32 + d4];
        acc.x += va.x; acc.y += va.y; acc.z += va.z; acc.w += va.w;
    }
    int len = s1 - s0;
    float rd = 1.0f / (float)(len > 1 ? len : 1);
    acc.x *= rd; acc.y *= rd; acc.z *= rd; acc.w *= rd;
    hn4[(size_t)node * 32 + d4] = acc;
}

// ---------------------------------------------------------------------------
// Kernel 2: pre = relu(h @ W_self + hn @ W_neigh + b) * snorm  (in place over
// hn rows) + per-feature BN partial sums.
// ---------------------------------------------------------------------------
constexpr int NPB = 8;  // nodes per block-tile

__global__ __launch_bounds__(128) void gemm_kernel(
        const float* __restrict__ h,
        const float* __restrict__ snorm,
        const float* __restrict__ Wself,
        const float* __restrict__ Wneigh,
        const float* __restrict__ bias,
        float* hn_pre,                    // aliased: read hn, write pre
        float* __restrict__ sums,
        float* __restrict__ sumsq) {
    __shared__ float hs[NPB][D];
    __shared__ float hn[NPB][D];
    int d = threadIdx.x;

    float lsum = 0.f, lsq = 0.f;
    int ntiles = N_NODES / NPB;  // 5000, exact

    for (int tile = blockIdx.x; tile < ntiles; tile += gridDim.x) {
        int n0 = tile * NPB;
        #pragma unroll
        for (int i = 0; i < NPB; i++) {
            int n = n0 + i;
            hs[i][d] = h[(size_t)n * D + d];
            hn[i][d] = hn_pre[(size_t)n * D + d];
        }
        __syncthreads();

        float acc[NPB];
        #pragma unroll
        for (int i = 0; i < NPB; i++) acc[i] = 0.f;

        for (int k = 0; k < D; k++) {
            float ws = Wself[k * D + d];
            float wn = Wneigh[k * D + d];
            #pragma unroll
            for (int i = 0; i < NPB; i++) {
                acc[i] = fmaf(hs[i][k], ws, acc[i]);
                acc[i] = fmaf(hn[i][k], wn, acc[i]);
            }
        }

        float bb = bias[d];
        #pragma unroll
        for (int i = 0; i < NPB; i++) {
            int n = n0 + i;
            float v = acc[i] + bb;
            v = fmaxf(v, 0.f);
            v *= snorm[n];
            hn_pre[(size_t)n * D + d] = v;
            lsum += v;
            lsq  += v * v;
        }
        __syncthreads();
    }
    atomicAdd(&sums[d], lsum);
    atomicAdd(&sumsq[d], lsq);
}

// ---------------------------------------------------------------------------
// Kernel 3: fold BN statistics into affine scale/shift (128 threads).
// ---------------------------------------------------------------------------
__global__ void stats_kernel(const float* __restrict__ sums,
                             const float* __restrict__ sumsq,
                             const float* __restrict__ gamma,
                             const float* __restrict__ beta,
                             float* __restrict__ scale,
                             float* __restrict__ shift) {
    int d = threadIdx.x;
    float invN = 1.0f / (float)N_NODES;
    float mean = sums[d] * invN;
    float var  = sumsq[d] * invN - mean * mean;
    float sc   = gamma[d] * rsqrtf(var + BN_EPS);
    scale[d] = sc;
    shift[d] = beta[d] - mean * sc;
}

// ---------------------------------------------------------------------------
// Kernel 4: out = h + pre*scale[d] + shift[d]   (in-place on d_out, float4)
// ---------------------------------------------------------------------------
__global__ void final_kernel(const float* __restrict__ h,
                             const float* __restrict__ scale,
                             const float* __restrict__ shift,
                             float* __restrict__ out) {
    int idx = blockIdx.x * blockDim.x + threadIdx.x;  // over N*D/4
    int total = N_NODES * D / 4;
    if (idx >= total) return;
    const float4 hv = reinterpret_cast<const float4*>(h)[idx];
    float4 ov = reinterpret_cast<float4*>(out)[idx];
    int d0 = (idx * 4) & 127;
    ov.x = hv.x + ov.x * scale[d0 + 0] + shift[d0 + 0];
    ov.y = hv.y + ov.y * scale[d0 + 1] + shift[d0 + 1];
    ov.z = hv.z + ov.z * scale[d0 + 2] + shift[d0 + 2];
    ov.w = hv.w + ov.w * scale[d0 + 3] + shift[d0 + 3];
    reinterpret_cast<float4*>(out)[idx] = ov;
}

// ---------------------------------------------------------------------------
extern "C" void kernel_launch(void* const* d_in, const int* in_sizes, int n_in,
                              void* d_out, int out_size, void* d_ws, size_t ws_size,
                              hipStream_t stream) {
    const float* h      = (const float*)d_in[0];
    const float* snorm  = (const float*)d_in[1];
    const float* Wself  = (const float*)d_in[2];
    const float* Wneigh = (const float*)d_in[3];
    const float* bias   = (const float*)d_in[4];
    const float* gamma  = (const float*)d_in[5];
    const float* beta   = (const float*)d_in[6];
    const int*   src    = (const int*)d_in[7];
    const int*   dst    = (const int*)d_in[8];
    float* out = (float*)d_out;

    // workspace layout:
    // zeroed:   [ deg_i : N int ][ cursor : N int ][ sums : D f ][ sumsq : D f ]
    // unzeroed: [ row_start : N+1 int ][ esrc : E int ][ scale : D f ][ shift : D f ]
    int*   deg_i     = (int*)d_ws;
    int*   cursor    = deg_i + N_NODES;
    float* sums      = (float*)(cursor + N_NODES);
    float* sumsq     = sums + D;
    int*   row_start = (int*)(sumsq + D);
    int*   esrc      = row_start + (N_NODES + 1);
    float* scale     = (float*)(esrc + N_EDGES);
    float* shift     = scale + D;

    size_t zero_bytes = (size_t)(2 * N_NODES + 2 * D) * sizeof(float);
    hipMemsetAsync(d_ws, 0, zero_bytes, stream);

    // 1a) degree histogram
    {
        int block = 256, grid = (N_EDGES + block - 1) / block;
        hist_kernel<<<grid, block, 0, stream>>>(dst, deg_i);
    }
    // 1b) prefix scan -> row_start
    scan_kernel<<<1, 1024, 0, stream>>>(deg_i, row_start);
    // 1c) bucket fill
    {
        int block = 256, grid = (N_EDGES + block - 1) / block;
        fill_kernel<<<grid, block, 0, stream>>>(src, dst, row_start, cursor, esrc);
    }
    // 1d) gather + mean -> h_neigh (written into d_out)
    {
        int total = N_NODES * 32;
        int block = 256, grid = (total + block - 1) / block;
        gather_kernel<<<grid, block, 0, stream>>>(
            (const float4*)h, row_start, esrc, (float4*)out);
    }
    // 2) dual GEMM + relu + snorm + BN partial stats (in place on d_out)
    gemm_kernel<<<1024, 128, 0, stream>>>(h, snorm, Wself, Wneigh, bias,
                                          out, sums, sumsq);
    // 3) BN stats -> affine
    stats_kernel<<<1, D, 0, stream>>>(sums, sumsq, gamma, beta, scale, shift);
    // 4) finalize: residual + BN affine
    {
        int total = N_NODES * D / 4;
        int block = 256, grid = (total + block - 1) / block;
        final_kernel<<<grid, block, 0, stream>>>(h, scale, shift, out);
    }
}

// Round 3
// 318.903 us; speedup vs baseline: 1.5741x; 1.2833x over previous
//
#include <hip/hip_runtime.h>
#include <hip/hip_bf16.h>

constexpr int N_NODES = 40000;
constexpr int N_EDGES = 640000;
constexpr int D = 128;
constexpr float BN_EPS = 1e-5f;

static_assert(N_EDGES == N_NODES * D / 8, "hist_cvt fusion assumes equal ranges");

// ---------------------------------------------------------------------------
// Kernel 1a: fused degree histogram + h -> bf16 conversion.
// Thread e: atomicAdd(deg[dst[e]]) AND converts 8 floats of h to packed bf16.
// (Both ranges are exactly 640000.)
// ---------------------------------------------------------------------------
__device__ __forceinline__ unsigned bf16_rne(float f) {
    unsigned b = __float_as_uint(f);
    return (b + 0x7FFFu + ((b >> 16) & 1u)) >> 16;
}

__global__ void hist_cvt_kernel(const int* __restrict__ dst,
                                int* __restrict__ deg_i,
                                const float4* __restrict__ h4,
                                uint4* __restrict__ hb4) {
    int e = blockIdx.x * blockDim.x + threadIdx.x;
    if (e >= N_EDGES) return;
    atomicAdd(&deg_i[dst[e]], 1);
    // convert floats [8e, 8e+8) -> bf16
    float4 a = h4[2 * e];
    float4 b = h4[2 * e + 1];
    uint4 o;
    o.x = bf16_rne(a.x) | (bf16_rne(a.y) << 16);
    o.y = bf16_rne(a.z) | (bf16_rne(a.w) << 16);
    o.z = bf16_rne(b.x) | (bf16_rne(b.y) << 16);
    o.w = bf16_rne(b.z) | (bf16_rne(b.w) << 16);
    hb4[e] = o;
}

// ---------------------------------------------------------------------------
// Kernel 1b: exclusive prefix scan of deg_i -> row_start (single block, 1024t)
// ---------------------------------------------------------------------------
__global__ __launch_bounds__(1024) void scan_kernel(const int* __restrict__ deg_i,
                                                    int* __restrict__ row_start) {
    __shared__ int part[1024];
    const int CH = 40;  // 1024*40 >= 40000
    int t = threadIdx.x;
    int base = t * CH;
    int s = 0;
    for (int i = 0; i < CH; i++) {
        int idx = base + i;
        if (idx < N_NODES) s += deg_i[idx];
    }
    part[t] = s;
    __syncthreads();
    for (int off = 1; off < 1024; off <<= 1) {
        int v = (t >= off) ? part[t - off] : 0;
        __syncthreads();
        part[t] += v;
        __syncthreads();
    }
    int run = part[t] - s;
    for (int i = 0; i < CH; i++) {
        int idx = base + i;
        if (idx < N_NODES) {
            row_start[idx] = run;
            run += deg_i[idx];
        }
    }
    if (t == 1023) row_start[N_NODES] = part[1023];
}

// ---------------------------------------------------------------------------
// Kernel 1c: bucket-fill sorted src list (CSR column indices)
// ---------------------------------------------------------------------------
__global__ void fill_kernel(const int* __restrict__ src,
                            const int* __restrict__ dst,
                            const int* __restrict__ row_start,
                            int* __restrict__ cursor,
                            int* __restrict__ esrc) {
    int e = blockIdx.x * blockDim.x + threadIdx.x;
    if (e >= N_EDGES) return;
    int t = dst[e];
    int p = atomicAdd(&cursor[t], 1);
    esrc[row_start[t] + p] = src[e];
}

// ---------------------------------------------------------------------------
// Kernel 1d: gather + mean from bf16 h. 16 lanes per node, uint4 (8 bf16)
// per lane. Accumulate fp32, write h_neigh (fp32) into d_out.
// ---------------------------------------------------------------------------
__device__ __forceinline__ float bflo(unsigned w) { return __uint_as_float(w << 16); }
__device__ __forceinline__ float bfhi(unsigned w) { return __uint_as_float(w & 0xFFFF0000u); }

__global__ void gather_kernel(const uint4* __restrict__ hb4,
                              const int* __restrict__ row_start,
                              const int* __restrict__ esrc,
                              float4* __restrict__ hn4) {
    int gid = blockIdx.x * blockDim.x + threadIdx.x;
    int node = gid >> 4;
    int lane = gid & 15;
    if (node >= N_NODES) return;
    int s0 = row_start[node];
    int s1 = row_start[node + 1];
    float acc[8] = {0.f, 0.f, 0.f, 0.f, 0.f, 0.f, 0.f, 0.f};
    int j = s0;
    for (; j + 1 < s1; j += 2) {
        int a = esrc[j];
        int b = esrc[j + 1];
        uint4 va = hb4[(size_t)a * 16 + lane];
        uint4 vb = hb4[(size_t)b * 16 + lane];
        acc[0] += bflo(va.x); acc[1] += bfhi(va.x);
        acc[2] += bflo(va.y); acc[3] += bfhi(va.y);
        acc[4] += bflo(va.z); acc[5] += bfhi(va.z);
        acc[6] += bflo(va.w); acc[7] += bfhi(va.w);
        acc[0] += bflo(vb.x); acc[1] += bfhi(vb.x);
        acc[2] += bflo(vb.y); acc[3] += bfhi(vb.y);
        acc[4] += bflo(vb.z); acc[5] += bfhi(vb.z);
        acc[6] += bflo(vb.w); acc[7] += bfhi(vb.w);
    }
    if (j < s1) {
        int a = esrc[j];
        uint4 va = hb4[(size_t)a * 16 + lane];
        acc[0] += bflo(va.x); acc[1] += bfhi(va.x);
        acc[2] += bflo(va.y); acc[3] += bfhi(va.y);
        acc[4] += bflo(va.z); acc[5] += bfhi(va.z);
        acc[6] += bflo(va.w); acc[7] += bfhi(va.w);
    }
    int len = s1 - s0;
    float rd = 1.0f / (float)(len > 1 ? len : 1);
    float4 o0 = make_float4(acc[0] * rd, acc[1] * rd, acc[2] * rd, acc[3] * rd);
    float4 o1 = make_float4(acc[4] * rd, acc[5] * rd, acc[6] * rd, acc[7] * rd);
    hn4[(size_t)node * 32 + lane * 2 + 0] = o0;
    hn4[(size_t)node * 32 + lane * 2 + 1] = o1;
}

// ---------------------------------------------------------------------------
// Kernel 2: register-tiled fused dual GEMM.
// Block: 256 threads, tile 64 nodes x 128 features. Thread (tx=t&15, ty=t>>4)
// computes 4 nodes (ty*4+i) x 8 features (tx+16j). K staged in 32-chunks.
// A tiles: LDS stride 36 (2-way max on reads, free). W tiles: stride 132
// (compute reads are per-k b32 broadcasts, conflict-free).
// Epilogue: +bias, relu, *snorm, store pre (in place over hn), BN partials
// reduced in LDS then one global atomic pair per feature per block.
// ---------------------------------------------------------------------------
constexpr int TN = 64;   // nodes per block tile
constexpr int KC = 32;   // k chunk

__global__ __launch_bounds__(256) void gemm_kernel(
        const float* __restrict__ h,
        const float* __restrict__ snorm,
        const float* __restrict__ Wself,
        const float* __restrict__ Wneigh,
        const float* __restrict__ bias,
        float* hn_pre,                    // aliased: read hn, write pre
        float* __restrict__ sums,
        float* __restrict__ sumsq) {
    __shared__ float hs[TN][KC + 4];
    __shared__ float hn[TN][KC + 4];
    __shared__ float Wsh[KC][D + 4];
    __shared__ float Wnh[KC][D + 4];
    __shared__ float sums_l[D];
    __shared__ float sumsq_l[D];

    int t  = threadIdx.x;
    int tx = t & 15;
    int ty = t >> 4;
    int n0 = blockIdx.x * TN;

    if (t < D) { sums_l[t] = 0.f; sumsq_l[t] = 0.f; }

    float acc[4][8];
    #pragma unroll
    for (int i = 0; i < 4; i++)
        #pragma unroll
        for (int j = 0; j < 8; j++) acc[i][j] = 0.f;

    for (int kc = 0; kc < D; kc += KC) {
        __syncthreads();
        // stage A tiles (h and hn), 2 passes of 32 rows
        {
            int c = (t & 7) * 4;
            #pragma unroll
            for (int p = 0; p < 2; p++) {
                int n = p * 32 + (t >> 3);
                float4 v = *(const float4*)&h[(size_t)(n0 + n) * D + kc + c];
                *(float4*)&hs[n][c] = v;
                float4 u = *(const float4*)&hn_pre[(size_t)(n0 + n) * D + kc + c];
                *(float4*)&hn[n][c] = u;
            }
        }
        // stage W chunks, 4 passes of 8 k-rows
        {
            int c = (t & 31) * 4;
            #pragma unroll
            for (int p = 0; p < 4; p++) {
                int kl = p * 8 + (t >> 5);
                *(float4*)&Wsh[kl][c] = *(const float4*)&Wself[(size_t)(kc + kl) * D + c];
                *(float4*)&Wnh[kl][c] = *(const float4*)&Wneigh[(size_t)(kc + kl) * D + c];
            }
        }
        __syncthreads();

        #pragma unroll 4
        for (int kl = 0; kl < KC; kl++) {
            float as_[4], an_[4], ws[8], wn[8];
            #pragma unroll
            for (int i = 0; i < 4; i++) {
                as_[i] = hs[ty * 4 + i][kl];
                an_[i] = hn[ty * 4 + i][kl];
            }
            #pragma unroll
            for (int j = 0; j < 8; j++) {
                ws[j] = Wsh[kl][tx + 16 * j];
                wn[j] = Wnh[kl][tx + 16 * j];
            }
            #pragma unroll
            for (int i = 0; i < 4; i++)
                #pragma unroll
                for (int j = 0; j < 8; j++) {
                    acc[i][j] = fmaf(as_[i], ws[j], acc[i][j]);
                    acc[i][j] = fmaf(an_[i], wn[j], acc[i][j]);
                }
        }
    }

    // epilogue
    float sn[4];
    #pragma unroll
    for (int i = 0; i < 4; i++) sn[i] = snorm[n0 + ty * 4 + i];
    float psum[8], psq[8];
    #pragma unroll
    for (int j = 0; j < 8; j++) { psum[j] = 0.f; psq[j] = 0.f; }

    #pragma unroll
    for (int j = 0; j < 8; j++) {
        int dcol = tx + 16 * j;
        float bb = bias[dcol];
        #pragma unroll
        for (int i = 0; i < 4; i++) {
            int n = n0 + ty * 4 + i;
            float v = acc[i][j] + bb;
            v = fmaxf(v, 0.f);
            v *= sn[i];
            hn_pre[(size_t)n * D + dcol] = v;
            psum[j] += v;
            psq[j]  += v * v;
        }
    }
    __syncthreads();  // sums_l zeroed before loop; all barriers since passed
    #pragma unroll
    for (int j = 0; j < 8; j++) {
        atomicAdd(&sums_l[tx + 16 * j], psum[j]);
        atomicAdd(&sumsq_l[tx + 16 * j], psq[j]);
    }
    __syncthreads();
    if (t < D) {
        atomicAdd(&sums[t], sums_l[t]);
        atomicAdd(&sumsq[t], sumsq_l[t]);
    }
}

// ---------------------------------------------------------------------------
// Kernel 3: finalize with fused BN stats: out = h + pre*scale + shift.
// scale/shift recomputed per thread from 1KB L2-resident arrays (free).
// ---------------------------------------------------------------------------
__global__ void final_kernel(const float4* __restrict__ h4,
                             const float4* __restrict__ sums4,
                             const float4* __restrict__ sumsq4,
                             const float4* __restrict__ gamma4,
                             const float4* __restrict__ beta4,
                             float4* __restrict__ out4) {
    int idx = blockIdx.x * blockDim.x + threadIdx.x;  // over N*D/4
    int total = N_NODES * D / 4;
    if (idx >= total) return;
    int d4 = idx & 31;  // which float4 of the 128-feature row
    float4 s  = sums4[d4];
    float4 sq = sumsq4[d4];
    float4 g  = gamma4[d4];
    float4 bt = beta4[d4];
    const float invN = 1.0f / (float)N_NODES;
    float4 hv = h4[idx];
    float4 ov = out4[idx];
    float m, var, sc;
    m = s.x * invN; var = sq.x * invN - m * m; sc = g.x * rsqrtf(var + BN_EPS);
    ov.x = hv.x + (ov.x - m) * sc + bt.x;
    m = s.y * invN; var = sq.y * invN - m * m; sc = g.y * rsqrtf(var + BN_EPS);
    ov.y = hv.y + (ov.y - m) * sc + bt.y;
    m = s.z * invN; var = sq.z * invN - m * m; sc = g.z * rsqrtf(var + BN_EPS);
    ov.z = hv.z + (ov.z - m) * sc + bt.z;
    m = s.w * invN; var = sq.w * invN - m * m; sc = g.w * rsqrtf(var + BN_EPS);
    ov.w = hv.w + (ov.w - m) * sc + bt.w;
    out4[idx] = ov;
}

// ---------------------------------------------------------------------------
extern "C" void kernel_launch(void* const* d_in, const int* in_sizes, int n_in,
                              void* d_out, int out_size, void* d_ws, size_t ws_size,
                              hipStream_t stream) {
    const float* h      = (const float*)d_in[0];
    const float* snorm  = (const float*)d_in[1];
    const float* Wself  = (const float*)d_in[2];
    const float* Wneigh = (const float*)d_in[3];
    const float* bias   = (const float*)d_in[4];
    const float* gamma  = (const float*)d_in[5];
    const float* beta   = (const float*)d_in[6];
    const int*   src    = (const int*)d_in[7];
    const int*   dst    = (const int*)d_in[8];
    float* out = (float*)d_out;

    // workspace layout:
    // zeroed:   [ deg_i : N int ][ cursor : N int ][ sums : D f ][ sumsq : D f ]
    // unzeroed: [ row_start : N+1 int ][ esrc : E int ][ pad ][ hb : N*D bf16 ]
    int*   deg_i     = (int*)d_ws;
    int*   cursor    = deg_i + N_NODES;
    float* sums      = (float*)(cursor + N_NODES);
    float* sumsq     = sums + D;
    int*   row_start = (int*)(sumsq + D);
    int*   esrc      = row_start + (N_NODES + 1);
    size_t off       = (size_t)(esrc + N_EDGES) - (size_t)d_ws;
    off = (off + 15) & ~(size_t)15;  // 16B align for uint4
    unsigned short* hb = (unsigned short*)((char*)d_ws + off);

    size_t zero_bytes = (size_t)(2 * N_NODES + 2 * D) * sizeof(float);
    hipMemsetAsync(d_ws, 0, zero_bytes, stream);

    // 1a) degree histogram + bf16 convert (both ranges exactly 640000)
    hist_cvt_kernel<<<N_EDGES / 256, 256, 0, stream>>>(
        dst, deg_i, (const float4*)h, (uint4*)hb);
    // 1b) prefix scan -> row_start
    scan_kernel<<<1, 1024, 0, stream>>>(deg_i, row_start);
    // 1c) bucket fill
    fill_kernel<<<N_EDGES / 256, 256, 0, stream>>>(src, dst, row_start, cursor, esrc);
    // 1d) gather + mean -> h_neigh (fp32, written into d_out)
    gather_kernel<<<(N_NODES * 16 + 255) / 256, 256, 0, stream>>>(
        (const uint4*)hb, row_start, esrc, (float4*)out);
    // 2) register-tiled dual GEMM + relu + snorm + BN partial stats (in place)
    gemm_kernel<<<N_NODES / TN, 256, 0, stream>>>(h, snorm, Wself, Wneigh, bias,
                                                  out, sums, sumsq);
    // 3) finalize: residual + BN (stats folded per-thread)
    {
        int total = N_NODES * D / 4;
        final_kernel<<<(total + 255) / 256, 256, 0, stream>>>(
            (const float4*)h, (const float4*)sums, (const float4*)sumsq,
            (const float4*)gamma, (const float4*)beta, (float4*)out);
    }
}

// Round 4
// 226.070 us; speedup vs baseline: 2.2205x; 1.4106x over previous
//
#include <hip/hip_runtime.h>
#include <hip/hip_bf16.h>

constexpr int N_NODES = 40000;
constexpr int N_EDGES = 640000;
constexpr int D = 128;
constexpr float BN_EPS = 1e-5f;
constexpr int SCAN_BLOCKS = 157;  // ceil(40000/256)

typedef __attribute__((ext_vector_type(8))) short short8;
typedef __attribute__((ext_vector_type(4))) float f32x4;

static_assert(N_EDGES == N_NODES * D / 8, "hist_cvt fusion assumes equal ranges");

__device__ __forceinline__ unsigned bf16_rne(float f) {
    unsigned b = __float_as_uint(f);
    return (b + 0x7FFFu + ((b >> 16) & 1u)) >> 16;
}

// ---------------------------------------------------------------------------
// Kernel 1a: fused degree histogram + h -> bf16 conversion.
// ---------------------------------------------------------------------------
__global__ void hist_cvt_kernel(const int* __restrict__ dst,
                                int* __restrict__ deg_i,
                                const float4* __restrict__ h4,
                                uint4* __restrict__ hb4) {
    int e = blockIdx.x * blockDim.x + threadIdx.x;
    if (e >= N_EDGES) return;
    atomicAdd(&deg_i[dst[e]], 1);
    float4 a = h4[2 * e];
    float4 b = h4[2 * e + 1];
    uint4 o;
    o.x = bf16_rne(a.x) | (bf16_rne(a.y) << 16);
    o.y = bf16_rne(a.z) | (bf16_rne(a.w) << 16);
    o.z = bf16_rne(b.x) | (bf16_rne(b.y) << 16);
    o.w = bf16_rne(b.z) | (bf16_rne(b.w) << 16);
    hb4[e] = o;
}

// ---------------------------------------------------------------------------
// Kernel 1a': W -> bf16, transposed: Wbt[n][k] = (k<128 ? Wself : Wneigh)[k][n]
// ---------------------------------------------------------------------------
__global__ void wcvt_kernel(const float* __restrict__ Wself,
                            const float* __restrict__ Wneigh,
                            unsigned short* __restrict__ Wbt) {
    int idx = blockIdx.x * blockDim.x + threadIdx.x;  // 128*256 = 32768
    int n = idx >> 8;
    int k = idx & 255;
    float v = (k < D) ? Wself[(size_t)k * D + n] : Wneigh[(size_t)(k - D) * D + n];
    Wbt[idx] = (unsigned short)bf16_rne(v);
}

// ---------------------------------------------------------------------------
// 3-phase exclusive scan of deg_i -> row_start
// ---------------------------------------------------------------------------
__global__ __launch_bounds__(256) void scan1_kernel(const int* __restrict__ deg_i,
                                                    int* __restrict__ partials) {
    __shared__ int sh[256];
    int t = threadIdx.x;
    int i = blockIdx.x * 256 + t;
    sh[t] = (i < N_NODES) ? deg_i[i] : 0;
    __syncthreads();
    for (int off = 128; off >= 1; off >>= 1) {
        if (t < off) sh[t] += sh[t + off];
        __syncthreads();
    }
    if (t == 0) partials[blockIdx.x] = sh[0];
}

__global__ __launch_bounds__(256) void scan2_kernel(int* __restrict__ partials,
                                                    int* __restrict__ row_start) {
    __shared__ int sh[256];
    int t = threadIdx.x;
    int v = (t < SCAN_BLOCKS) ? partials[t] : 0;
    sh[t] = v;
    __syncthreads();
    for (int off = 1; off < 256; off <<= 1) {
        int u = (t >= off) ? sh[t - off] : 0;
        __syncthreads();
        sh[t] += u;
        __syncthreads();
    }
    if (t < SCAN_BLOCKS) partials[t] = sh[t] - v;  // exclusive block offset
    if (t == 255) row_start[N_NODES] = sh[255];
}

__global__ __launch_bounds__(256) void scan3_kernel(const int* __restrict__ deg_i,
                                                    const int* __restrict__ partials,
                                                    int* __restrict__ row_start) {
    __shared__ int sh[256];
    int t = threadIdx.x;
    int i = blockIdx.x * 256 + t;
    int v = (i < N_NODES) ? deg_i[i] : 0;
    sh[t] = v;
    __syncthreads();
    for (int off = 1; off < 256; off <<= 1) {
        int u = (t >= off) ? sh[t - off] : 0;
        __syncthreads();
        sh[t] += u;
        __syncthreads();
    }
    if (i < N_NODES) row_start[i] = sh[t] - v + partials[blockIdx.x];
}

// ---------------------------------------------------------------------------
// Kernel 1c: bucket-fill sorted src list (CSR column indices)
// ---------------------------------------------------------------------------
__global__ void fill_kernel(const int* __restrict__ src,
                            const int* __restrict__ dst,
                            const int* __restrict__ row_start,
                            int* __restrict__ cursor,
                            int* __restrict__ esrc) {
    int e = blockIdx.x * blockDim.x + threadIdx.x;
    if (e >= N_EDGES) return;
    int t = dst[e];
    int p = atomicAdd(&cursor[t], 1);
    esrc[row_start[t] + p] = src[e];
}

// ---------------------------------------------------------------------------
// Kernel 1d: gather + mean from bf16 h. 16 lanes per node, uint4 per lane.
// Writes h_neigh (fp32) into d_out.
// ---------------------------------------------------------------------------
__device__ __forceinline__ float bflo(unsigned w) { return __uint_as_float(w << 16); }
__device__ __forceinline__ float bfhi(unsigned w) { return __uint_as_float(w & 0xFFFF0000u); }

__global__ void gather_kernel(const uint4* __restrict__ hb4,
                              const int* __restrict__ row_start,
                              const int* __restrict__ esrc,
                              float4* __restrict__ hn4) {
    int gid = blockIdx.x * blockDim.x + threadIdx.x;
    int node = gid >> 4;
    int lane = gid & 15;
    if (node >= N_NODES) return;
    int s0 = row_start[node];
    int s1 = row_start[node + 1];
    float acc[8] = {0.f, 0.f, 0.f, 0.f, 0.f, 0.f, 0.f, 0.f};
    int j = s0;
    for (; j + 1 < s1; j += 2) {
        int a = esrc[j];
        int b = esrc[j + 1];
        uint4 va = hb4[(size_t)a * 16 + lane];
        uint4 vb = hb4[(size_t)b * 16 + lane];
        acc[0] += bflo(va.x); acc[1] += bfhi(va.x);
        acc[2] += bflo(va.y); acc[3] += bfhi(va.y);
        acc[4] += bflo(va.z); acc[5] += bfhi(va.z);
        acc[6] += bflo(va.w); acc[7] += bfhi(va.w);
        acc[0] += bflo(vb.x); acc[1] += bfhi(vb.x);
        acc[2] += bflo(vb.y); acc[3] += bfhi(vb.y);
        acc[4] += bflo(vb.z); acc[5] += bfhi(vb.z);
        acc[6] += bflo(vb.w); acc[7] += bfhi(vb.w);
    }
    if (j < s1) {
        int a = esrc[j];
        uint4 va = hb4[(size_t)a * 16 + lane];
        acc[0] += bflo(va.x); acc[1] += bfhi(va.x);
        acc[2] += bflo(va.y); acc[3] += bfhi(va.y);
        acc[4] += bflo(va.z); acc[5] += bfhi(va.z);
        acc[6] += bflo(va.w); acc[7] += bfhi(va.w);
    }
    int len = s1 - s0;
    float rd = 1.0f / (float)(len > 1 ? len : 1);
    float4 o0 = make_float4(acc[0] * rd, acc[1] * rd, acc[2] * rd, acc[3] * rd);
    float4 o1 = make_float4(acc[4] * rd, acc[5] * rd, acc[6] * rd, acc[7] * rd);
    hn4[(size_t)node * 32 + lane * 2 + 0] = o0;
    hn4[(size_t)node * 32 + lane * 2 + 1] = o1;
}

// ---------------------------------------------------------------------------
// Kernel 2: MFMA dual GEMM, K=256 concat: pre = relu([h|hn] @ [Ws;Wn] + b)*sn.
// 625 blocks x 128 threads (2 waves). Wave handles 32 rows x 128 cols:
// 2 rowgroups x 8 coltiles of 16x16x32 bf16 MFMA, K = 8 k-tiles.
// A frags direct from global (hb bf16 / hn fp32 inline-packed); B frags from
// L1/L2-resident Wbt (64KB). No LDS except BN-stat reduction.
// A-frag layout: A[m=lane&15][k=(lane>>4)*8+j]; B[k=(lane>>4)*8+j][n=lane&15];
// C/D: col=lane&15, row=(lane>>4)*4+reg (m89/m91-verified).
// ---------------------------------------------------------------------------
__global__ __launch_bounds__(128) void gemm_mfma_kernel(
        const uint4* __restrict__ hb4,      // bf16 h, 16 granules/row
        const float4* hn4,                  // fp32 hn (= d_out), 32 f4/row
        const uint4* __restrict__ wbt4,     // bf16 Wbt[128][256], 32 granules/row
        const float* __restrict__ snorm,
        const float* __restrict__ bias,
        float* pre,                         // = d_out (in-place over hn rows)
        float* __restrict__ sums,
        float* __restrict__ sumsq) {
    __shared__ float sums_l[D];
    __shared__ float sumsq_l[D];
    int t = threadIdx.x;
    int lane = t & 63;
    int wid = t >> 6;
    int n = lane & 15;
    int kg = lane >> 4;
    int row_base = blockIdx.x * 64 + wid * 32;

    if (t < D) { sums_l[t] = 0.f; sumsq_l[t] = 0.f; }
    __syncthreads();

    // ---- A fragments: 2 rowgroups x 8 k-tiles ----
    short8 a[2][8];
    #pragma unroll
    for (int rg = 0; rg < 2; rg++) {
        int row = row_base + rg * 16 + n;
        #pragma unroll
        for (int kt = 0; kt < 4; kt++) {  // k in [0,128): self path, bf16 direct
            uint4 v = hb4[(size_t)row * 16 + kt * 4 + kg];
            a[rg][kt] = __builtin_bit_cast(short8, v);
        }
        #pragma unroll
        for (int kt = 0; kt < 4; kt++) {  // k in [128,256): neigh path, pack fp32
            float4 f0 = hn4[(size_t)row * 32 + kt * 8 + kg * 2 + 0];
            float4 f1 = hn4[(size_t)row * 32 + kt * 8 + kg * 2 + 1];
            uint4 p;
            p.x = bf16_rne(f0.x) | (bf16_rne(f0.y) << 16);
            p.y = bf16_rne(f0.z) | (bf16_rne(f0.w) << 16);
            p.z = bf16_rne(f1.x) | (bf16_rne(f1.y) << 16);
            p.w = bf16_rne(f1.z) | (bf16_rne(f1.w) << 16);
            a[rg][4 + kt] = __builtin_bit_cast(short8, p);
        }
    }

    // ---- MFMA main loop ----
    f32x4 acc[2][8];
    #pragma unroll
    for (int rg = 0; rg < 2; rg++)
        #pragma unroll
        for (int ct = 0; ct < 8; ct++)
            acc[rg][ct] = (f32x4){0.f, 0.f, 0.f, 0.f};

    #pragma unroll
    for (int ct = 0; ct < 8; ct++) {
        #pragma unroll
        for (int kt = 0; kt < 8; kt++) {
            uint4 bv = wbt4[(size_t)(ct * 16 + n) * 32 + kt * 4 + kg];
            short8 b = __builtin_bit_cast(short8, bv);
            acc[0][ct] = __builtin_amdgcn_mfma_f32_16x16x32_bf16(a[0][kt], b, acc[0][ct], 0, 0, 0);
            acc[1][ct] = __builtin_amdgcn_mfma_f32_16x16x32_bf16(a[1][kt], b, acc[1][ct], 0, 0, 0);
        }
    }

    // ---- epilogue: +bias, relu, *snorm, store pre, BN partials ----
    float snv[2][4];
    #pragma unroll
    for (int rg = 0; rg < 2; rg++)
        #pragma unroll
        for (int r = 0; r < 4; r++)
            snv[rg][r] = snorm[row_base + rg * 16 + kg * 4 + r];

    #pragma unroll
    for (int ct = 0; ct < 8; ct++) {
        int col = ct * 16 + n;
        float bb = bias[col];
        float csum = 0.f, csq = 0.f;
        #pragma unroll
        for (int rg = 0; rg < 2; rg++) {
            #pragma unroll
            for (int r = 0; r < 4; r++) {
                int row = row_base + rg * 16 + kg * 4 + r;
                float v = acc[rg][ct][r] + bb;
                v = fmaxf(v, 0.f);
                v *= snv[rg][r];
                pre[(size_t)row * D + col] = v;
                csum += v;
                csq += v * v;
            }
        }
        csum += __shfl_xor(csum, 16); csq += __shfl_xor(csq, 16);
        csum += __shfl_xor(csum, 32); csq += __shfl_xor(csq, 32);
        if (kg == 0) {
            atomicAdd(&sums_l[col], csum);
            atomicAdd(&sumsq_l[col], csq);
        }
    }
    __syncthreads();
    if (t < D) {
        atomicAdd(&sums[t], sums_l[t]);
        atomicAdd(&sumsq[t], sumsq_l[t]);
    }
}

// ---------------------------------------------------------------------------
// Kernel 3: finalize with fused BN stats: out = h + (pre-mean)*scale + beta.
// ---------------------------------------------------------------------------
__global__ void final_kernel(const float4* __restrict__ h4,
                             const float4* __restrict__ sums4,
                             const float4* __restrict__ sumsq4,
                             const float4* __restrict__ gamma4,
                             const float4* __restrict__ beta4,
                             float4* __restrict__ out4) {
    int idx = blockIdx.x * blockDim.x + threadIdx.x;  // over N*D/4
    int total = N_NODES * D / 4;
    if (idx >= total) return;
    int d4 = idx & 31;
    float4 s  = sums4[d4];
    float4 sq = sumsq4[d4];
    float4 g  = gamma4[d4];
    float4 bt = beta4[d4];
    const float invN = 1.0f / (float)N_NODES;
    float4 hv = h4[idx];
    float4 ov = out4[idx];
    float m, var, sc;
    m = s.x * invN; var = sq.x * invN - m * m; sc = g.x * rsqrtf(var + BN_EPS);
    ov.x = hv.x + (ov.x - m) * sc + bt.x;
    m = s.y * invN; var = sq.y * invN - m * m; sc = g.y * rsqrtf(var + BN_EPS);
    ov.y = hv.y + (ov.y - m) * sc + bt.y;
    m = s.z * invN; var = sq.z * invN - m * m; sc = g.z * rsqrtf(var + BN_EPS);
    ov.z = hv.z + (ov.z - m) * sc + bt.z;
    m = s.w * invN; var = sq.w * invN - m * m; sc = g.w * rsqrtf(var + BN_EPS);
    ov.w = hv.w + (ov.w - m) * sc + bt.w;
    out4[idx] = ov;
}

// ---------------------------------------------------------------------------
extern "C" void kernel_launch(void* const* d_in, const int* in_sizes, int n_in,
                              void* d_out, int out_size, void* d_ws, size_t ws_size,
                              hipStream_t stream) {
    const float* h      = (const float*)d_in[0];
    const float* snorm  = (const float*)d_in[1];
    const float* Wself  = (const float*)d_in[2];
    const float* Wneigh = (const float*)d_in[3];
    const float* bias   = (const float*)d_in[4];
    const float* gamma  = (const float*)d_in[5];
    const float* beta   = (const float*)d_in[6];
    const int*   src    = (const int*)d_in[7];
    const int*   dst    = (const int*)d_in[8];
    float* out = (float*)d_out;

    // ws layout:
    // zeroed:   [ deg_i : N int ][ cursor : N int ][ sums : D f ][ sumsq : D f ]
    // unzeroed: [ row_start : N+1 ][ partials : 160 ][ esrc : E ][ Wbt ][ hb ]
    int*   deg_i     = (int*)d_ws;
    int*   cursor    = deg_i + N_NODES;
    float* sums      = (float*)(cursor + N_NODES);
    float* sumsq     = sums + D;
    int*   row_start = (int*)(sumsq + D);
    int*   partials  = row_start + (N_NODES + 1);
    int*   esrc      = partials + 160;
    size_t off       = (size_t)((char*)(esrc + N_EDGES) - (char*)d_ws);
    off = (off + 15) & ~(size_t)15;
    unsigned short* Wbt = (unsigned short*)((char*)d_ws + off);
    unsigned short* hb  = Wbt + (size_t)2 * D * D;  // 2*128*128 bf16 = 64KB

    size_t zero_bytes = (size_t)(2 * N_NODES + 2 * D) * sizeof(float);
    hipMemsetAsync(d_ws, 0, zero_bytes, stream);

    // 1a) degree histogram + h -> bf16
    hist_cvt_kernel<<<N_EDGES / 256, 256, 0, stream>>>(
        dst, deg_i, (const float4*)h, (uint4*)hb);
    // 1a') W -> bf16 transposed
    wcvt_kernel<<<(2 * D * D) / 256, 256, 0, stream>>>(Wself, Wneigh, Wbt);
    // 1b) 3-phase scan -> row_start
    scan1_kernel<<<SCAN_BLOCKS, 256, 0, stream>>>(deg_i, partials);
    scan2_kernel<<<1, 256, 0, stream>>>(partials, row_start);
    scan3_kernel<<<SCAN_BLOCKS, 256, 0, stream>>>(deg_i, partials, row_start);
    // 1c) bucket fill
    fill_kernel<<<N_EDGES / 256, 256, 0, stream>>>(src, dst, row_start, cursor, esrc);
    // 1d) gather + mean -> h_neigh fp32 (into d_out)
    gather_kernel<<<(N_NODES * 16) / 256, 256, 0, stream>>>(
        (const uint4*)hb, row_start, esrc, (float4*)out);
    // 2) MFMA dual GEMM + relu + snorm + BN partials (in place on d_out)
    gemm_mfma_kernel<<<N_NODES / 64, 128, 0, stream>>>(
        (const uint4*)hb, (const float4*)out, (const uint4*)Wbt,
        snorm, bias, out, sums, sumsq);
    // 3) finalize: residual + BN
    final_kernel<<<(N_NODES * D / 4) / 256, 256, 0, stream>>>(
        (const float4*)h, (const float4*)sums, (const float4*)sumsq,
        (const float4*)gamma, (const float4*)beta, (float4*)out);
}

// Round 5
// 211.242 us; speedup vs baseline: 2.3764x; 1.0702x over previous
//
#include <hip/hip_runtime.h>
#include <hip/hip_bf16.h>

constexpr int N_NODES = 40000;
constexpr int N_EDGES = 640000;
constexpr int D = 128;
constexpr float BN_EPS = 1e-5f;
constexpr int SCAN_BLOCKS = 157;  // ceil(40000/256)

typedef __attribute__((ext_vector_type(8))) short short8;
typedef __attribute__((ext_vector_type(4))) float f32x4;

static_assert(N_EDGES == N_NODES * D / 8, "hist_cvt fusion assumes equal ranges");

__device__ __forceinline__ unsigned bf16_rne(float f) {
    unsigned b = __float_as_uint(f);
    return (b + 0x7FFFu + ((b >> 16) & 1u)) >> 16;
}
__device__ __forceinline__ float bflo(unsigned w) { return __uint_as_float(w << 16); }
__device__ __forceinline__ float bfhi(unsigned w) { return __uint_as_float(w & 0xFFFF0000u); }

// ---------------------------------------------------------------------------
// Kernel 1a: fused degree histogram + h -> bf16 conversion.
// ---------------------------------------------------------------------------
__global__ void hist_cvt_kernel(const int* __restrict__ dst,
                                int* __restrict__ deg_i,
                                const float4* __restrict__ h4,
                                uint4* __restrict__ hb4) {
    int e = blockIdx.x * blockDim.x + threadIdx.x;
    if (e >= N_EDGES) return;
    atomicAdd(&deg_i[dst[e]], 1);
    float4 a = h4[2 * e];
    float4 b = h4[2 * e + 1];
    uint4 o;
    o.x = bf16_rne(a.x) | (bf16_rne(a.y) << 16);
    o.y = bf16_rne(a.z) | (bf16_rne(a.w) << 16);
    o.z = bf16_rne(b.x) | (bf16_rne(b.y) << 16);
    o.w = bf16_rne(b.z) | (bf16_rne(b.w) << 16);
    hb4[e] = o;
}

// ---------------------------------------------------------------------------
// Kernel 1a': W -> bf16 in MFMA frag-major layout.
// Granule G = (ct*8+kt)*64 + kg*16 + n holds 8 bf16: j=0..7 of
// Wcat[k = kt*32+kg*8+j][col = ct*16+n], Wcat = [Wself; Wneigh] (K=256).
// So gemm's B-frag for (ct,kt) is granules [(ct*8+kt)*64 + lane] — lane-
// sequential, enabling coalesced staging and conflict-free ds_read_b128.
// ---------------------------------------------------------------------------
__global__ void wcvt_kernel(const float* __restrict__ Wself,
                            const float* __restrict__ Wneigh,
                            uint4* __restrict__ wfrag) {
    int G = blockIdx.x * blockDim.x + threadIdx.x;  // 4096 granules
    int l = G & 63;
    int tile = G >> 6;
    int kg = l >> 4;
    int n = l & 15;
    int ct = tile >> 3;
    int kt = tile & 7;
    int k0 = kt * 32 + kg * 8;
    int col = ct * 16 + n;
    unsigned w[8];
    #pragma unroll
    for (int j = 0; j < 8; j++) {
        int k = k0 + j;
        float v = (k < D) ? Wself[(size_t)k * D + col]
                          : Wneigh[(size_t)(k - D) * D + col];
        w[j] = bf16_rne(v);
    }
    uint4 o;
    o.x = w[0] | (w[1] << 16);
    o.y = w[2] | (w[3] << 16);
    o.z = w[4] | (w[5] << 16);
    o.w = w[6] | (w[7] << 16);
    wfrag[G] = o;
}

// ---------------------------------------------------------------------------
// 3-phase exclusive scan of deg_i -> row_start
// ---------------------------------------------------------------------------
__global__ __launch_bounds__(256) void scan1_kernel(const int* __restrict__ deg_i,
                                                    int* __restrict__ partials) {
    __shared__ int sh[256];
    int t = threadIdx.x;
    int i = blockIdx.x * 256 + t;
    sh[t] = (i < N_NODES) ? deg_i[i] : 0;
    __syncthreads();
    for (int off = 128; off >= 1; off >>= 1) {
        if (t < off) sh[t] += sh[t + off];
        __syncthreads();
    }
    if (t == 0) partials[blockIdx.x] = sh[0];
}

__global__ __launch_bounds__(256) void scan2_kernel(int* __restrict__ partials,
                                                    int* __restrict__ row_start) {
    __shared__ int sh[256];
    int t = threadIdx.x;
    int v = (t < SCAN_BLOCKS) ? partials[t] : 0;
    sh[t] = v;
    __syncthreads();
    for (int off = 1; off < 256; off <<= 1) {
        int u = (t >= off) ? sh[t - off] : 0;
        __syncthreads();
        sh[t] += u;
        __syncthreads();
    }
    if (t < SCAN_BLOCKS) partials[t] = sh[t] - v;  // exclusive block offset
    if (t == 255) row_start[N_NODES] = sh[255];
}

__global__ __launch_bounds__(256) void scan3_kernel(const int* __restrict__ deg_i,
                                                    const int* __restrict__ partials,
                                                    int* __restrict__ row_start) {
    __shared__ int sh[256];
    int t = threadIdx.x;
    int i = blockIdx.x * 256 + t;
    int v = (i < N_NODES) ? deg_i[i] : 0;
    sh[t] = v;
    __syncthreads();
    for (int off = 1; off < 256; off <<= 1) {
        int u = (t >= off) ? sh[t - off] : 0;
        __syncthreads();
        sh[t] += u;
        __syncthreads();
    }
    if (i < N_NODES) row_start[i] = sh[t] - v + partials[blockIdx.x];
}

// ---------------------------------------------------------------------------
// Kernel 1c: bucket-fill sorted src list (CSR column indices)
// ---------------------------------------------------------------------------
__global__ void fill_kernel(const int* __restrict__ src,
                            const int* __restrict__ dst,
                            const int* __restrict__ row_start,
                            int* __restrict__ cursor,
                            int* __restrict__ esrc) {
    int e = blockIdx.x * blockDim.x + threadIdx.x;
    if (e >= N_EDGES) return;
    int t = dst[e];
    int p = atomicAdd(&cursor[t], 1);
    esrc[row_start[t] + p] = src[e];
}

// ---------------------------------------------------------------------------
// Kernel 1d: gather + mean from bf16 h; writes h_neigh as bf16 (hnb).
// 16 lanes per node, one uint4 (8 bf16) per lane; fp32 accumulate.
// ---------------------------------------------------------------------------
__global__ void gather_kernel(const uint4* __restrict__ hb4,
                              const int* __restrict__ row_start,
                              const int* __restrict__ esrc,
                              uint4* __restrict__ hnb4) {
    int gid = blockIdx.x * blockDim.x + threadIdx.x;
    int node = gid >> 4;
    int lane = gid & 15;
    if (node >= N_NODES) return;
    int s0 = row_start[node];
    int s1 = row_start[node + 1];
    float acc[8] = {0.f, 0.f, 0.f, 0.f, 0.f, 0.f, 0.f, 0.f};
    int j = s0;
    for (; j + 1 < s1; j += 2) {
        int a = esrc[j];
        int b = esrc[j + 1];
        uint4 va = hb4[(size_t)a * 16 + lane];
        uint4 vb = hb4[(size_t)b * 16 + lane];
        acc[0] += bflo(va.x); acc[1] += bfhi(va.x);
        acc[2] += bflo(va.y); acc[3] += bfhi(va.y);
        acc[4] += bflo(va.z); acc[5] += bfhi(va.z);
        acc[6] += bflo(va.w); acc[7] += bfhi(va.w);
        acc[0] += bflo(vb.x); acc[1] += bfhi(vb.x);
        acc[2] += bflo(vb.y); acc[3] += bfhi(vb.y);
        acc[4] += bflo(vb.z); acc[5] += bfhi(vb.z);
        acc[6] += bflo(vb.w); acc[7] += bfhi(vb.w);
    }
    if (j < s1) {
        int a = esrc[j];
        uint4 va = hb4[(size_t)a * 16 + lane];
        acc[0] += bflo(va.x); acc[1] += bfhi(va.x);
        acc[2] += bflo(va.y); acc[3] += bfhi(va.y);
        acc[4] += bflo(va.z); acc[5] += bfhi(va.z);
        acc[6] += bflo(va.w); acc[7] += bfhi(va.w);
    }
    int len = s1 - s0;
    float rd = 1.0f / (float)(len > 1 ? len : 1);
    uint4 o;
    o.x = bf16_rne(acc[0] * rd) | (bf16_rne(acc[1] * rd) << 16);
    o.y = bf16_rne(acc[2] * rd) | (bf16_rne(acc[3] * rd) << 16);
    o.z = bf16_rne(acc[4] * rd) | (bf16_rne(acc[5] * rd) << 16);
    o.w = bf16_rne(acc[6] * rd) | (bf16_rne(acc[7] * rd) << 16);
    hnb4[(size_t)node * 16 + lane] = o;
}

// ---------------------------------------------------------------------------
// Kernel 2: MFMA dual GEMM v3. Grid = 625 rowtiles x 2 colhalves.
// Block = 256 threads (4 waves) = 64 rows x 64 cols. W staged frag-major into
// LDS (32KB, coalesced copy, conflict-free ds_read_b128). Wave w: 16 rows
// (rowbase = rowtile*64 + w*16) x 64 cols: 4 coltiles x 8 ktiles MFMA, with
// only 8 global A loads per wave (self 4 from hb, neigh 4 from hnb).
// Epilogue: +bias, relu, *snorm, store pre as bf16, BN partials via shfl+LDS.
// A[m=lane&15][k=(lane>>4)*8+j]; C/D: col=lane&15, row=(lane>>4)*4+reg.
// ---------------------------------------------------------------------------
__global__ __launch_bounds__(256) void gemm_mfma_kernel(
        const uint4* __restrict__ hb4,      // bf16 h, 16 granules/row
        const uint4* __restrict__ hnb4,     // bf16 hn, 16 granules/row
        const uint4* __restrict__ wfrag,    // frag-major bf16 W, 4096 granules
        const float* __restrict__ snorm,
        const float* __restrict__ bias,
        unsigned short* __restrict__ pre_b, // bf16 pre, [N][D]
        float* __restrict__ sums,
        float* __restrict__ sumsq) {
    __shared__ uint4 ldsW[2048];            // 32 KB: this col-half's 4 coltiles
    __shared__ float sums_l[64];
    __shared__ float sumsq_l[64];

    int t = threadIdx.x;
    int lane = t & 63;
    int wid = t >> 6;
    int n = lane & 15;
    int kg = lane >> 4;
    int rowtile = blockIdx.x >> 1;
    int cbt = blockIdx.x & 1;
    int cb = cbt * 64;
    int row_base = rowtile * 64 + wid * 16;
    int row = row_base + n;

    if (t < 64) { sums_l[t] = 0.f; sumsq_l[t] = 0.f; }

    // ---- A fragments: 8 k-tiles (4 self + 4 neigh), direct from global ----
    short8 a[8];
    #pragma unroll
    for (int kt = 0; kt < 4; kt++) {
        uint4 v = hb4[(size_t)row * 16 + kt * 4 + kg];
        a[kt] = __builtin_bit_cast(short8, v);
    }
    #pragma unroll
    for (int kt = 0; kt < 4; kt++) {
        uint4 v = hnb4[(size_t)row * 16 + kt * 4 + kg];
        a[4 + kt] = __builtin_bit_cast(short8, v);
    }

    // ---- stage this col-half's W frags into LDS (coalesced) ----
    #pragma unroll
    for (int i = 0; i < 8; i++) {
        int g = i * 256 + t;
        ldsW[g] = wfrag[cbt * 2048 + g];
    }
    __syncthreads();

    // ---- MFMA main loop: 4 coltiles x 8 ktiles ----
    f32x4 acc[4];
    #pragma unroll
    for (int lt = 0; lt < 4; lt++) acc[lt] = (f32x4){0.f, 0.f, 0.f, 0.f};

    #pragma unroll
    for (int lt = 0; lt < 4; lt++) {
        #pragma unroll
        for (int kt = 0; kt < 8; kt++) {
            short8 b = __builtin_bit_cast(short8, ldsW[(lt * 8 + kt) * 64 + lane]);
            acc[lt] = __builtin_amdgcn_mfma_f32_16x16x32_bf16(a[kt], b, acc[lt], 0, 0, 0);
        }
    }

    // ---- epilogue ----
    float snv[4];
    #pragma unroll
    for (int r = 0; r < 4; r++) snv[r] = snorm[row_base + kg * 4 + r];

    #pragma unroll
    for (int lt = 0; lt < 4; lt++) {
        int col = cb + lt * 16 + n;
        float bb = bias[col];
        float csum = 0.f, csq = 0.f;
        #pragma unroll
        for (int r = 0; r < 4; r++) {
            int rr = row_base + kg * 4 + r;
            float v = acc[lt][r] + bb;
            v = fmaxf(v, 0.f);
            v *= snv[r];
            pre_b[(size_t)rr * D + col] = (unsigned short)bf16_rne(v);
            csum += v;
            csq += v * v;
        }
        csum += __shfl_xor(csum, 16); csq += __shfl_xor(csq, 16);
        csum += __shfl_xor(csum, 32); csq += __shfl_xor(csq, 32);
        if (kg == 0) {
            atomicAdd(&sums_l[lt * 16 + n], csum);
            atomicAdd(&sumsq_l[lt * 16 + n], csq);
        }
    }
    __syncthreads();
    if (t < 64) {
        atomicAdd(&sums[cb + t], sums_l[t]);
        atomicAdd(&sumsq[cb + t], sumsq_l[t]);
    }
}

// ---------------------------------------------------------------------------
// Kernel 3: finalize: out = h + (pre - mean)*scale + beta (stats folded).
// pre read as bf16 (uint2 = 4 features).
// ---------------------------------------------------------------------------
__global__ void final_kernel(const float4* __restrict__ h4,
                             const uint2* __restrict__ preb2,
                             const float4* __restrict__ sums4,
                             const float4* __restrict__ sumsq4,
                             const float4* __restrict__ gamma4,
                             const float4* __restrict__ beta4,
                             float4* __restrict__ out4) {
    int idx = blockIdx.x * blockDim.x + threadIdx.x;  // over N*D/4
    int total = N_NODES * D / 4;
    if (idx >= total) return;
    int d4 = idx & 31;
    float4 s  = sums4[d4];
    float4 sq = sumsq4[d4];
    float4 g  = gamma4[d4];
    float4 bt = beta4[d4];
    const float invN = 1.0f / (float)N_NODES;
    float4 hv = h4[idx];
    uint2 pb = preb2[idx];
    float p0 = bflo(pb.x), p1 = bfhi(pb.x), p2 = bflo(pb.y), p3 = bfhi(pb.y);
    float4 ov;
    float m, var, sc;
    m = s.x * invN; var = sq.x * invN - m * m; sc = g.x * rsqrtf(var + BN_EPS);
    ov.x = hv.x + (p0 - m) * sc + bt.x;
    m = s.y * invN; var = sq.y * invN - m * m; sc = g.y * rsqrtf(var + BN_EPS);
    ov.y = hv.y + (p1 - m) * sc + bt.y;
    m = s.z * invN; var = sq.z * invN - m * m; sc = g.z * rsqrtf(var + BN_EPS);
    ov.z = hv.z + (p2 - m) * sc + bt.z;
    m = s.w * invN; var = sq.w * invN - m * m; sc = g.w * rsqrtf(var + BN_EPS);
    ov.w = hv.w + (p3 - m) * sc + bt.w;
    out4[idx] = ov;
}

// ---------------------------------------------------------------------------
extern "C" void kernel_launch(void* const* d_in, const int* in_sizes, int n_in,
                              void* d_out, int out_size, void* d_ws, size_t ws_size,
                              hipStream_t stream) {
    const float* h      = (const float*)d_in[0];
    const float* snorm  = (const float*)d_in[1];
    const float* Wself  = (const float*)d_in[2];
    const float* Wneigh = (const float*)d_in[3];
    const float* bias   = (const float*)d_in[4];
    const float* gamma  = (const float*)d_in[5];
    const float* beta   = (const float*)d_in[6];
    const int*   src    = (const int*)d_in[7];
    const int*   dst    = (const int*)d_in[8];
    float* out = (float*)d_out;

    // ws layout:
    // zeroed:   [ deg_i : N int ][ cursor : N int ][ sums : D f ][ sumsq : D f ]
    // unzeroed: [ row_start : N+1 ][ partials : 160 ][ esrc : E ]
    //           [ wfrag : 64KB ][ hb : 10.2MB ][ hnb : 10.2MB ][ pre_b : 10.2MB ]
    int*   deg_i     = (int*)d_ws;
    int*   cursor    = deg_i + N_NODES;
    float* sums      = (float*)(cursor + N_NODES);
    float* sumsq     = sums + D;
    int*   row_start = (int*)(sumsq + D);
    int*   partials  = row_start + (N_NODES + 1);
    int*   esrc      = partials + 160;
    size_t off       = (size_t)((char*)(esrc + N_EDGES) - (char*)d_ws);
    off = (off + 15) & ~(size_t)15;
    uint4* wfrag = (uint4*)((char*)d_ws + off);
    uint4* hb4   = wfrag + 4096;
    uint4* hnb4  = hb4 + N_NODES * (D / 8);
    unsigned short* pre_b = (unsigned short*)(hnb4 + N_NODES * (D / 8));

    size_t zero_bytes = (size_t)(2 * N_NODES + 2 * D) * sizeof(float);
    hipMemsetAsync(d_ws, 0, zero_bytes, stream);

    // 1a) degree histogram + h -> bf16
    hist_cvt_kernel<<<N_EDGES / 256, 256, 0, stream>>>(
        dst, deg_i, (const float4*)h, hb4);
    // 1a') W -> frag-major bf16
    wcvt_kernel<<<16, 256, 0, stream>>>(Wself, Wneigh, wfrag);
    // 1b) 3-phase scan -> row_start
    scan1_kernel<<<SCAN_BLOCKS, 256, 0, stream>>>(deg_i, partials);
    scan2_kernel<<<1, 256, 0, stream>>>(partials, row_start);
    scan3_kernel<<<SCAN_BLOCKS, 256, 0, stream>>>(deg_i, partials, row_start);
    // 1c) bucket fill
    fill_kernel<<<N_EDGES / 256, 256, 0, stream>>>(src, dst, row_start, cursor, esrc);
    // 1d) gather + mean -> hnb (bf16)
    gather_kernel<<<(N_NODES * 16) / 256, 256, 0, stream>>>(
        hb4, row_start, esrc, hnb4);
    // 2) MFMA dual GEMM + relu + snorm + BN partials -> pre_b (bf16)
    gemm_mfma_kernel<<<(N_NODES / 64) * 2, 256, 0, stream>>>(
        hb4, hnb4, wfrag, snorm, bias, pre_b, sums, sumsq);
    // 3) finalize: residual + BN
    final_kernel<<<(N_NODES * D / 4) / 256, 256, 0, stream>>>(
        (const float4*)h, (const uint2*)pre_b, (const float4*)sums,
        (const float4*)sumsq, (const float4*)gamma, (const float4*)beta,
        (float4*)out);
}

// Round 6
// 208.453 us; speedup vs baseline: 2.4082x; 1.0134x over previous
//
#include <hip/hip_runtime.h>
#include <hip/hip_bf16.h>

constexpr int N_NODES = 40000;
constexpr int N_EDGES = 640000;
constexpr int D = 128;
constexpr float BN_EPS = 1e-5f;
constexpr int SCAN_BLOCKS = 157;  // ceil(40000/256)

typedef __attribute__((ext_vector_type(8))) short short8;
typedef __attribute__((ext_vector_type(4))) float f32x4;

static_assert(N_EDGES == N_NODES * D / 8, "hist_cvt fusion assumes equal ranges");

__device__ __forceinline__ unsigned bf16_rne(float f) {
    unsigned b = __float_as_uint(f);
    return (b + 0x7FFFu + ((b >> 16) & 1u)) >> 16;
}
__device__ __forceinline__ float bflo(unsigned w) { return __uint_as_float(w << 16); }
__device__ __forceinline__ float bfhi(unsigned w) { return __uint_as_float(w & 0xFFFF0000u); }

// ---------------------------------------------------------------------------
// Kernel 1a: fused degree histogram + h -> bf16 conversion + (blocks 0..15)
// W -> frag-major bf16 conversion.
// W frag layout: granule G = (ct*8+kt)*64 + kg*16 + n holds j=0..7 of
// Wcat[k = kt*32+kg*8+j][col = ct*16+n], Wcat = [Wself; Wneigh] (K=256).
// ---------------------------------------------------------------------------
__global__ void hist_cvt_kernel(const int* __restrict__ dst,
                                int* __restrict__ deg_i,
                                const float4* __restrict__ h4,
                                uint4* __restrict__ hb4,
                                const float* __restrict__ Wself,
                                const float* __restrict__ Wneigh,
                                uint4* __restrict__ wfrag) {
    int e = blockIdx.x * blockDim.x + threadIdx.x;
    if (e >= N_EDGES) return;
    atomicAdd(&deg_i[dst[e]], 1);
    float4 a = h4[2 * e];
    float4 b = h4[2 * e + 1];
    uint4 o;
    o.x = bf16_rne(a.x) | (bf16_rne(a.y) << 16);
    o.y = bf16_rne(a.z) | (bf16_rne(a.w) << 16);
    o.z = bf16_rne(b.x) | (bf16_rne(b.y) << 16);
    o.w = bf16_rne(b.z) | (bf16_rne(b.w) << 16);
    hb4[e] = o;

    // first 16 blocks also build the 4096-granule frag-major W
    if (e < 4096) {
        int G = e;
        int l = G & 63;
        int tile = G >> 6;
        int kg = l >> 4;
        int n = l & 15;
        int ct = tile >> 3;
        int kt = tile & 7;
        int k0 = kt * 32 + kg * 8;
        int col = ct * 16 + n;
        unsigned w[8];
        #pragma unroll
        for (int j = 0; j < 8; j++) {
            int k = k0 + j;
            float v = (k < D) ? Wself[(size_t)k * D + col]
                              : Wneigh[(size_t)(k - D) * D + col];
            w[j] = bf16_rne(v);
        }
        uint4 ow;
        ow.x = w[0] | (w[1] << 16);
        ow.y = w[2] | (w[3] << 16);
        ow.z = w[4] | (w[5] << 16);
        ow.w = w[6] | (w[7] << 16);
        wfrag[G] = ow;
    }
}

// ---------------------------------------------------------------------------
// 3-phase exclusive scan of deg_i -> row_start
// ---------------------------------------------------------------------------
__global__ __launch_bounds__(256) void scan1_kernel(const int* __restrict__ deg_i,
                                                    int* __restrict__ partials) {
    __shared__ int sh[256];
    int t = threadIdx.x;
    int i = blockIdx.x * 256 + t;
    sh[t] = (i < N_NODES) ? deg_i[i] : 0;
    __syncthreads();
    for (int off = 128; off >= 1; off >>= 1) {
        if (t < off) sh[t] += sh[t + off];
        __syncthreads();
    }
    if (t == 0) partials[blockIdx.x] = sh[0];
}

__global__ __launch_bounds__(256) void scan2_kernel(int* __restrict__ partials,
                                                    int* __restrict__ row_start) {
    __shared__ int sh[256];
    int t = threadIdx.x;
    int v = (t < SCAN_BLOCKS) ? partials[t] : 0;
    sh[t] = v;
    __syncthreads();
    for (int off = 1; off < 256; off <<= 1) {
        int u = (t >= off) ? sh[t - off] : 0;
        __syncthreads();
        sh[t] += u;
        __syncthreads();
    }
    if (t < SCAN_BLOCKS) partials[t] = sh[t] - v;  // exclusive block offset
    if (t == 255) row_start[N_NODES] = sh[255];
}

__global__ __launch_bounds__(256) void scan3_kernel(const int* __restrict__ deg_i,
                                                    const int* __restrict__ partials,
                                                    int* __restrict__ row_start) {
    __shared__ int sh[256];
    int t = threadIdx.x;
    int i = blockIdx.x * 256 + t;
    int v = (i < N_NODES) ? deg_i[i] : 0;
    sh[t] = v;
    __syncthreads();
    for (int off = 1; off < 256; off <<= 1) {
        int u = (t >= off) ? sh[t - off] : 0;
        __syncthreads();
        sh[t] += u;
        __syncthreads();
    }
    if (i < N_NODES) row_start[i] = sh[t] - v + partials[blockIdx.x];
}

// ---------------------------------------------------------------------------
// Kernel 1c: bucket-fill sorted src list (CSR column indices)
// ---------------------------------------------------------------------------
__global__ void fill_kernel(const int* __restrict__ src,
                            const int* __restrict__ dst,
                            const int* __restrict__ row_start,
                            int* __restrict__ cursor,
                            int* __restrict__ esrc) {
    int e = blockIdx.x * blockDim.x + threadIdx.x;
    if (e >= N_EDGES) return;
    int t = dst[e];
    int p = atomicAdd(&cursor[t], 1);
    esrc[row_start[t] + p] = src[e];
}

// ---------------------------------------------------------------------------
// Kernel 1d: gather + mean, v3: ONE WAVE PER NODE.
// lane = (edge-slot es = lane>>4) x (granule g = lane&15). Each iteration
// processes 4 edges in parallel (one 256B row per edge-slot, coalesced 1KB
// per wave). Dependent-chain depth ~deg/4 instead of deg/2 with 4x the
// loads in flight. Edge-slot partials folded by shfl_xor(16/32); lanes with
// es==0 write the bf16 mean row.
// ---------------------------------------------------------------------------
__global__ __launch_bounds__(256) void gather_kernel(
        const uint4* __restrict__ hb4,
        const int* __restrict__ row_start,
        const int* __restrict__ esrc,
        uint4* __restrict__ hnb4) {
    int node = (blockIdx.x * blockDim.x + threadIdx.x) >> 6;
    int lane = threadIdx.x & 63;
    if (node >= N_NODES) return;
    int g  = lane & 15;   // granule within row
    int es = lane >> 4;   // edge slot 0..3
    int s0 = row_start[node];
    int s1 = row_start[node + 1];
    float acc[8] = {0.f, 0.f, 0.f, 0.f, 0.f, 0.f, 0.f, 0.f};
    for (int j = s0 + es; j < s1; j += 4) {
        int a = esrc[j];
        uint4 v = hb4[(size_t)a * 16 + g];
        acc[0] += bflo(v.x); acc[1] += bfhi(v.x);
        acc[2] += bflo(v.y); acc[3] += bfhi(v.y);
        acc[4] += bflo(v.z); acc[5] += bfhi(v.z);
        acc[6] += bflo(v.w); acc[7] += bfhi(v.w);
    }
    // fold the 4 edge-slots (lanes differing in bits 4,5)
    #pragma unroll
    for (int i = 0; i < 8; i++) {
        acc[i] += __shfl_xor(acc[i], 16);
        acc[i] += __shfl_xor(acc[i], 32);
    }
    if (es == 0) {
        int len = s1 - s0;
        float rd = 1.0f / (float)(len > 1 ? len : 1);
        uint4 o;
        o.x = bf16_rne(acc[0] * rd) | (bf16_rne(acc[1] * rd) << 16);
        o.y = bf16_rne(acc[2] * rd) | (bf16_rne(acc[3] * rd) << 16);
        o.z = bf16_rne(acc[4] * rd) | (bf16_rne(acc[5] * rd) << 16);
        o.w = bf16_rne(acc[6] * rd) | (bf16_rne(acc[7] * rd) << 16);
        hnb4[(size_t)node * 16 + g] = o;
    }
}

// ---------------------------------------------------------------------------
// Kernel 2: MFMA dual GEMM v3 (unchanged from round 5).
// Grid = 625 rowtiles x 2 colhalves, block = 256 threads (4 waves) =
// 64 rows x 64 cols. W staged frag-major into LDS (32KB), conflict-free
// ds_read_b128; 8 global A loads per wave; 32 MFMAs per wave.
// A[m=lane&15][k=(lane>>4)*8+j]; C/D: col=lane&15, row=(lane>>4)*4+reg.
// ---------------------------------------------------------------------------
__global__ __launch_bounds__(256) void gemm_mfma_kernel(
        const uint4* __restrict__ hb4,      // bf16 h, 16 granules/row
        const uint4* __restrict__ hnb4,     // bf16 hn, 16 granules/row
        const uint4* __restrict__ wfrag,    // frag-major bf16 W, 4096 granules
        const float* __restrict__ snorm,
        const float* __restrict__ bias,
        unsigned short* __restrict__ pre_b, // bf16 pre, [N][D]
        float* __restrict__ sums,
        float* __restrict__ sumsq) {
    __shared__ uint4 ldsW[2048];            // 32 KB: this col-half's 4 coltiles
    __shared__ float sums_l[64];
    __shared__ float sumsq_l[64];

    int t = threadIdx.x;
    int lane = t & 63;
    int wid = t >> 6;
    int n = lane & 15;
    int kg = lane >> 4;
    int rowtile = blockIdx.x >> 1;
    int cbt = blockIdx.x & 1;
    int cb = cbt * 64;
    int row_base = rowtile * 64 + wid * 16;
    int row = row_base + n;

    if (t < 64) { sums_l[t] = 0.f; sumsq_l[t] = 0.f; }

    // ---- A fragments: 8 k-tiles (4 self + 4 neigh), direct from global ----
    short8 a[8];
    #pragma unroll
    for (int kt = 0; kt < 4; kt++) {
        uint4 v = hb4[(size_t)row * 16 + kt * 4 + kg];
        a[kt] = __builtin_bit_cast(short8, v);
    }
    #pragma unroll
    for (int kt = 0; kt < 4; kt++) {
        uint4 v = hnb4[(size_t)row * 16 + kt * 4 + kg];
        a[4 + kt] = __builtin_bit_cast(short8, v);
    }

    // ---- stage this col-half's W frags into LDS (coalesced) ----
    #pragma unroll
    for (int i = 0; i < 8; i++) {
        int g = i * 256 + t;
        ldsW[g] = wfrag[cbt * 2048 + g];
    }
    __syncthreads();

    // ---- MFMA main loop: 4 coltiles x 8 ktiles ----
    f32x4 acc[4];
    #pragma unroll
    for (int lt = 0; lt < 4; lt++) acc[lt] = (f32x4){0.f, 0.f, 0.f, 0.f};

    #pragma unroll
    for (int lt = 0; lt < 4; lt++) {
        #pragma unroll
        for (int kt = 0; kt < 8; kt++) {
            short8 b = __builtin_bit_cast(short8, ldsW[(lt * 8 + kt) * 64 + lane]);
            acc[lt] = __builtin_amdgcn_mfma_f32_16x16x32_bf16(a[kt], b, acc[lt], 0, 0, 0);
        }
    }

    // ---- epilogue ----
    float snv[4];
    #pragma unroll
    for (int r = 0; r < 4; r++) snv[r] = snorm[row_base + kg * 4 + r];

    #pragma unroll
    for (int lt = 0; lt < 4; lt++) {
        int col = cb + lt * 16 + n;
        float bb = bias[col];
        float csum = 0.f, csq = 0.f;
        #pragma unroll
        for (int r = 0; r < 4; r++) {
            int rr = row_base + kg * 4 + r;
            float v = acc[lt][r] + bb;
            v = fmaxf(v, 0.f);
            v *= snv[r];
            pre_b[(size_t)rr * D + col] = (unsigned short)bf16_rne(v);
            csum += v;
            csq += v * v;
        }
        csum += __shfl_xor(csum, 16); csq += __shfl_xor(csq, 16);
        csum += __shfl_xor(csum, 32); csq += __shfl_xor(csq, 32);
        if (kg == 0) {
            atomicAdd(&sums_l[lt * 16 + n], csum);
            atomicAdd(&sumsq_l[lt * 16 + n], csq);
        }
    }
    __syncthreads();
    if (t < 64) {
        atomicAdd(&sums[cb + t], sums_l[t]);
        atomicAdd(&sumsq[cb + t], sumsq_l[t]);
    }
}

// ---------------------------------------------------------------------------
// Kernel 3: finalize: out = h + (pre - mean)*scale + beta (stats folded).
// ---------------------------------------------------------------------------
__global__ void final_kernel(const float4* __restrict__ h4,
                             const uint2* __restrict__ preb2,
                             const float4* __restrict__ sums4,
                             const float4* __restrict__ sumsq4,
                             const float4* __restrict__ gamma4,
                             const float4* __restrict__ beta4,
                             float4* __restrict__ out4) {
    int idx = blockIdx.x * blockDim.x + threadIdx.x;  // over N*D/4
    int total = N_NODES * D / 4;
    if (idx >= total) return;
    int d4 = idx & 31;
    float4 s  = sums4[d4];
    float4 sq = sumsq4[d4];
    float4 g  = gamma4[d4];
    float4 bt = beta4[d4];
    const float invN = 1.0f / (float)N_NODES;
    float4 hv = h4[idx];
    uint2 pb = preb2[idx];
    float p0 = bflo(pb.x), p1 = bfhi(pb.x), p2 = bflo(pb.y), p3 = bfhi(pb.y);
    float4 ov;
    float m, var, sc;
    m = s.x * invN; var = sq.x * invN - m * m; sc = g.x * rsqrtf(var + BN_EPS);
    ov.x = hv.x + (p0 - m) * sc + bt.x;
    m = s.y * invN; var = sq.y * invN - m * m; sc = g.y * rsqrtf(var + BN_EPS);
    ov.y = hv.y + (p1 - m) * sc + bt.y;
    m = s.z * invN; var = sq.z * invN - m * m; sc = g.z * rsqrtf(var + BN_EPS);
    ov.z = hv.z + (p2 - m) * sc + bt.z;
    m = s.w * invN; var = sq.w * invN - m * m; sc = g.w * rsqrtf(var + BN_EPS);
    ov.w = hv.w + (p3 - m) * sc + bt.w;
    out4[idx] = ov;
}

// ---------------------------------------------------------------------------
extern "C" void kernel_launch(void* const* d_in, const int* in_sizes, int n_in,
                              void* d_out, int out_size, void* d_ws, size_t ws_size,
                              hipStream_t stream) {
    const float* h      = (const float*)d_in[0];
    const float* snorm  = (const float*)d_in[1];
    const float* Wself  = (const float*)d_in[2];
    const float* Wneigh = (const float*)d_in[3];
    const float* bias   = (const float*)d_in[4];
    const float* gamma  = (const float*)d_in[5];
    const float* beta   = (const float*)d_in[6];
    const int*   src    = (const int*)d_in[7];
    const int*   dst    = (const int*)d_in[8];
    float* out = (float*)d_out;

    // ws layout:
    // zeroed:   [ deg_i : N int ][ cursor : N int ][ sums : D f ][ sumsq : D f ]
    // unzeroed: [ row_start : N+1 ][ partials : 160 ][ esrc : E ]
    //           [ wfrag : 64KB ][ hb : 10.2MB ][ hnb : 10.2MB ][ pre_b : 10.2MB ]
    int*   deg_i     = (int*)d_ws;
    int*   cursor    = deg_i + N_NODES;
    float* sums      = (float*)(cursor + N_NODES);
    float* sumsq     = sums + D;
    int*   row_start = (int*)(sumsq + D);
    int*   partials  = row_start + (N_NODES + 1);
    int*   esrc      = partials + 160;
    size_t off       = (size_t)((char*)(esrc + N_EDGES) - (char*)d_ws);
    off = (off + 15) & ~(size_t)15;
    uint4* wfrag = (uint4*)((char*)d_ws + off);
    uint4* hb4   = wfrag + 4096;
    uint4* hnb4  = hb4 + N_NODES * (D / 8);
    unsigned short* pre_b = (unsigned short*)(hnb4 + N_NODES * (D / 8));

    size_t zero_bytes = (size_t)(2 * N_NODES + 2 * D) * sizeof(float);
    hipMemsetAsync(d_ws, 0, zero_bytes, stream);

    // 1a) degree histogram + h -> bf16 + W -> frag-major bf16
    hist_cvt_kernel<<<N_EDGES / 256, 256, 0, stream>>>(
        dst, deg_i, (const float4*)h, hb4, Wself, Wneigh, wfrag);
    // 1b) 3-phase scan -> row_start
    scan1_kernel<<<SCAN_BLOCKS, 256, 0, stream>>>(deg_i, partials);
    scan2_kernel<<<1, 256, 0, stream>>>(partials, row_start);
    scan3_kernel<<<SCAN_BLOCKS, 256, 0, stream>>>(deg_i, partials, row_start);
    // 1c) bucket fill
    fill_kernel<<<N_EDGES / 256, 256, 0, stream>>>(src, dst, row_start, cursor, esrc);
    // 1d) gather + mean -> hnb (bf16), one wave per node
    gather_kernel<<<N_NODES / 4, 256, 0, stream>>>(hb4, row_start, esrc, hnb4);
    // 2) MFMA dual GEMM + relu + snorm + BN partials -> pre_b (bf16)
    gemm_mfma_kernel<<<(N_NODES / 64) * 2, 256, 0, stream>>>(
        hb4, hnb4, wfrag, snorm, bias, pre_b, sums, sumsq);
    // 3) finalize: residual + BN
    final_kernel<<<(N_NODES * D / 4) / 256, 256, 0, stream>>>(
        (const float4*)h, (const uint2*)pre_b, (const float4*)sums,
        (const float4*)sumsq, (const float4*)gamma, (const float4*)beta,
        (float4*)out);
}

// Round 7
// 207.838 us; speedup vs baseline: 2.4153x; 1.0030x over previous
//
#include <hip/hip_runtime.h>
#include <hip/hip_bf16.h>

constexpr int N_NODES = 40000;
constexpr int N_EDGES = 640000;
constexpr int D = 128;
constexpr float BN_EPS = 1e-5f;
constexpr int SCAN_BLOCKS = 157;  // ceil(40000/256)

typedef __attribute__((ext_vector_type(8))) short short8;
typedef __attribute__((ext_vector_type(4))) float f32x4;

static_assert(N_EDGES == N_NODES * D / 8, "hist_cvt fusion assumes equal ranges");

__device__ __forceinline__ unsigned bf16_rne(float f) {
    unsigned b = __float_as_uint(f);
    return (b + 0x7FFFu + ((b >> 16) & 1u)) >> 16;
}
__device__ __forceinline__ float bflo(unsigned w) { return __uint_as_float(w << 16); }
__device__ __forceinline__ float bfhi(unsigned w) { return __uint_as_float(w & 0xFFFF0000u); }

// ---------------------------------------------------------------------------
// Kernel 1a: fused degree histogram + h -> bf16 conversion + (first 4096
// threads) W -> frag-major bf16 conversion.
// W frag layout: granule G = (ct*8+kt)*64 + kg*16 + n holds j=0..7 of
// Wcat[k = kt*32+kg*8+j][col = ct*16+n], Wcat = [Wself; Wneigh] (K=256).
// ---------------------------------------------------------------------------
__global__ void hist_cvt_kernel(const int* __restrict__ dst,
                                int* __restrict__ deg_i,
                                const float4* __restrict__ h4,
                                uint4* __restrict__ hb4,
                                const float* __restrict__ Wself,
                                const float* __restrict__ Wneigh,
                                uint4* __restrict__ wfrag) {
    int e = blockIdx.x * blockDim.x + threadIdx.x;
    if (e >= N_EDGES) return;
    atomicAdd(&deg_i[dst[e]], 1);
    float4 a = h4[2 * e];
    float4 b = h4[2 * e + 1];
    uint4 o;
    o.x = bf16_rne(a.x) | (bf16_rne(a.y) << 16);
    o.y = bf16_rne(a.z) | (bf16_rne(a.w) << 16);
    o.z = bf16_rne(b.x) | (bf16_rne(b.y) << 16);
    o.w = bf16_rne(b.z) | (bf16_rne(b.w) << 16);
    hb4[e] = o;

    if (e < 4096) {
        int G = e;
        int l = G & 63;
        int tile = G >> 6;
        int kg = l >> 4;
        int n = l & 15;
        int ct = tile >> 3;
        int kt = tile & 7;
        int k0 = kt * 32 + kg * 8;
        int col = ct * 16 + n;
        unsigned w[8];
        #pragma unroll
        for (int j = 0; j < 8; j++) {
            int k = k0 + j;
            float v = (k < D) ? Wself[(size_t)k * D + col]
                              : Wneigh[(size_t)(k - D) * D + col];
            w[j] = bf16_rne(v);
        }
        uint4 ow;
        ow.x = w[0] | (w[1] << 16);
        ow.y = w[2] | (w[3] << 16);
        ow.z = w[4] | (w[5] << 16);
        ow.w = w[6] | (w[7] << 16);
        wfrag[G] = ow;
    }
}

// ---------------------------------------------------------------------------
// Scan phase 1: per-block sums of deg_i (raw, not exclusive).
// ---------------------------------------------------------------------------
__global__ __launch_bounds__(256) void scan1_kernel(const int* __restrict__ deg_i,
                                                    int* __restrict__ partials) {
    __shared__ int sh[256];
    int t = threadIdx.x;
    int i = blockIdx.x * 256 + t;
    sh[t] = (i < N_NODES) ? deg_i[i] : 0;
    __syncthreads();
    for (int off = 128; off >= 1; off >>= 1) {
        if (t < off) sh[t] += sh[t + off];
        __syncthreads();
    }
    if (t == 0) partials[blockIdx.x] = sh[0];
}

// ---------------------------------------------------------------------------
// Scan phase 2+3 fused: block b reduces partials[0..b) for its offset, then
// locally scans its 256 deg values -> row_start. Last block writes total.
// ---------------------------------------------------------------------------
__global__ __launch_bounds__(256) void scan23_kernel(const int* __restrict__ deg_i,
                                                     const int* __restrict__ partials,
                                                     int* __restrict__ row_start) {
    __shared__ int sh[256];
    __shared__ int offs;
    int t = threadIdx.x;
    int b = blockIdx.x;
    // offset = sum of partials[0..b)
    sh[t] = (t < b) ? partials[t] : 0;   // b <= 156 < 256, safe
    __syncthreads();
    for (int off = 128; off >= 1; off >>= 1) {
        if (t < off) sh[t] += sh[t + off];
        __syncthreads();
    }
    if (t == 0) offs = sh[0];
    __syncthreads();
    // local inclusive scan of this block's 256 deg values
    int i = b * 256 + t;
    int v = (i < N_NODES) ? deg_i[i] : 0;
    sh[t] = v;
    __syncthreads();
    for (int off = 1; off < 256; off <<= 1) {
        int u = (t >= off) ? sh[t - off] : 0;
        __syncthreads();
        sh[t] += u;
        __syncthreads();
    }
    if (i < N_NODES) row_start[i] = sh[t] - v + offs;
    if (b == SCAN_BLOCKS - 1 && t == 255) row_start[N_NODES] = sh[255] + offs;
}

// ---------------------------------------------------------------------------
// Kernel 1c: bucket-fill sorted src list (CSR column indices)
// ---------------------------------------------------------------------------
__global__ void fill_kernel(const int* __restrict__ src,
                            const int* __restrict__ dst,
                            const int* __restrict__ row_start,
                            int* __restrict__ cursor,
                            int* __restrict__ esrc) {
    int e = blockIdx.x * blockDim.x + threadIdx.x;
    if (e >= N_EDGES) return;
    int t = dst[e];
    int p = atomicAdd(&cursor[t], 1);
    esrc[row_start[t] + p] = src[e];
}

// ---------------------------------------------------------------------------
// Kernel 1d: gather + mean, one wave per node (4 edge-slots x 16 granules).
// ---------------------------------------------------------------------------
__global__ __launch_bounds__(256) void gather_kernel(
        const uint4* __restrict__ hb4,
        const int* __restrict__ row_start,
        const int* __restrict__ esrc,
        uint4* __restrict__ hnb4) {
    int node = (blockIdx.x * blockDim.x + threadIdx.x) >> 6;
    int lane = threadIdx.x & 63;
    if (node >= N_NODES) return;
    int g  = lane & 15;   // granule within row
    int es = lane >> 4;   // edge slot 0..3
    int s0 = row_start[node];
    int s1 = row_start[node + 1];
    float acc[8] = {0.f, 0.f, 0.f, 0.f, 0.f, 0.f, 0.f, 0.f};
    for (int j = s0 + es; j < s1; j += 4) {
        int a = esrc[j];
        uint4 v = hb4[(size_t)a * 16 + g];
        acc[0] += bflo(v.x); acc[1] += bfhi(v.x);
        acc[2] += bflo(v.y); acc[3] += bfhi(v.y);
        acc[4] += bflo(v.z); acc[5] += bfhi(v.z);
        acc[6] += bflo(v.w); acc[7] += bfhi(v.w);
    }
    #pragma unroll
    for (int i = 0; i < 8; i++) {
        acc[i] += __shfl_xor(acc[i], 16);
        acc[i] += __shfl_xor(acc[i], 32);
    }
    if (es == 0) {
        int len = s1 - s0;
        float rd = 1.0f / (float)(len > 1 ? len : 1);
        uint4 o;
        o.x = bf16_rne(acc[0] * rd) | (bf16_rne(acc[1] * rd) << 16);
        o.y = bf16_rne(acc[2] * rd) | (bf16_rne(acc[3] * rd) << 16);
        o.z = bf16_rne(acc[4] * rd) | (bf16_rne(acc[5] * rd) << 16);
        o.w = bf16_rne(acc[6] * rd) | (bf16_rne(acc[7] * rd) << 16);
        hnb4[(size_t)node * 16 + g] = o;
    }
}

// ---------------------------------------------------------------------------
// Kernel 2: MFMA dual GEMM. Grid = 625 rowtiles x 2 colhalves, block = 256
// threads (4 waves) = 64 rows x 64 cols. W staged frag-major into LDS (32KB),
// conflict-free ds_read_b128; 8 global A loads per wave; 32 MFMAs per wave.
// pre stored f32 into d_out (full 64B segments — avoids the b16 partial-line
// write-allocate RMW that regressed round 5).
// A[m=lane&15][k=(lane>>4)*8+j]; C/D: col=lane&15, row=(lane>>4)*4+reg.
// ---------------------------------------------------------------------------
__global__ __launch_bounds__(256) void gemm_mfma_kernel(
        const uint4* __restrict__ hb4,      // bf16 h, 16 granules/row
        const uint4* __restrict__ hnb4,     // bf16 hn, 16 granules/row
        const uint4* __restrict__ wfrag,    // frag-major bf16 W, 4096 granules
        const float* __restrict__ snorm,
        const float* __restrict__ bias,
        float* __restrict__ pre,            // f32 pre = d_out, [N][D]
        float* __restrict__ sums,
        float* __restrict__ sumsq) {
    __shared__ uint4 ldsW[2048];            // 32 KB: this col-half's 4 coltiles
    __shared__ float sums_l[64];
    __shared__ float sumsq_l[64];

    int t = threadIdx.x;
    int lane = t & 63;
    int wid = t >> 6;
    int n = lane & 15;
    int kg = lane >> 4;
    int rowtile = blockIdx.x >> 1;
    int cbt = blockIdx.x & 1;
    int cb = cbt * 64;
    int row_base = rowtile * 64 + wid * 16;
    int row = row_base + n;

    if (t < 64) { sums_l[t] = 0.f; sumsq_l[t] = 0.f; }

    // ---- A fragments: 8 k-tiles (4 self + 4 neigh), direct from global ----
    short8 a[8];
    #pragma unroll
    for (int kt = 0; kt < 4; kt++) {
        uint4 v = hb4[(size_t)row * 16 + kt * 4 + kg];
        a[kt] = __builtin_bit_cast(short8, v);
    }
    #pragma unroll
    for (int kt = 0; kt < 4; kt++) {
        uint4 v = hnb4[(size_t)row * 16 + kt * 4 + kg];
        a[4 + kt] = __builtin_bit_cast(short8, v);
    }

    // ---- stage this col-half's W frags into LDS (coalesced) ----
    #pragma unroll
    for (int i = 0; i < 8; i++) {
        int g = i * 256 + t;
        ldsW[g] = wfrag[cbt * 2048 + g];
    }
    __syncthreads();

    // ---- MFMA main loop: 4 coltiles x 8 ktiles ----
    f32x4 acc[4];
    #pragma unroll
    for (int lt = 0; lt < 4; lt++) acc[lt] = (f32x4){0.f, 0.f, 0.f, 0.f};

    #pragma unroll
    for (int lt = 0; lt < 4; lt++) {
        #pragma unroll
        for (int kt = 0; kt < 8; kt++) {
            short8 b = __builtin_bit_cast(short8, ldsW[(lt * 8 + kt) * 64 + lane]);
            acc[lt] = __builtin_amdgcn_mfma_f32_16x16x32_bf16(a[kt], b, acc[lt], 0, 0, 0);
        }
    }

    // ---- epilogue ----
    float snv[4];
    #pragma unroll
    for (int r = 0; r < 4; r++) snv[r] = snorm[row_base + kg * 4 + r];

    #pragma unroll
    for (int lt = 0; lt < 4; lt++) {
        int col = cb + lt * 16 + n;
        float bb = bias[col];
        float csum = 0.f, csq = 0.f;
        #pragma unroll
        for (int r = 0; r < 4; r++) {
            int rr = row_base + kg * 4 + r;
            float v = acc[lt][r] + bb;
            v = fmaxf(v, 0.f);
            v *= snv[r];
            pre[(size_t)rr * D + col] = v;
            csum += v;
            csq += v * v;
        }
        csum += __shfl_xor(csum, 16); csq += __shfl_xor(csq, 16);
        csum += __shfl_xor(csum, 32); csq += __shfl_xor(csq, 32);
        if (kg == 0) {
            atomicAdd(&sums_l[lt * 16 + n], csum);
            atomicAdd(&sumsq_l[lt * 16 + n], csq);
        }
    }
    __syncthreads();
    if (t < 64) {
        atomicAdd(&sums[cb + t], sums_l[t]);
        atomicAdd(&sumsq[cb + t], sumsq_l[t]);
    }
}

// ---------------------------------------------------------------------------
// Kernel 3: finalize in place on d_out: out = h + (pre - mean)*scale + beta.
// ---------------------------------------------------------------------------
__global__ void final_kernel(const float4* __restrict__ h4,
                             const float4* __restrict__ sums4,
                             const float4* __restrict__ sumsq4,
                             const float4* __restrict__ gamma4,
                             const float4* __restrict__ beta4,
                             float4* __restrict__ out4) {
    int idx = blockIdx.x * blockDim.x + threadIdx.x;  // over N*D/4
    int total = N_NODES * D / 4;
    if (idx >= total) return;
    int d4 = idx & 31;
    float4 s  = sums4[d4];
    float4 sq = sumsq4[d4];
    float4 g  = gamma4[d4];
    float4 bt = beta4[d4];
    const float invN = 1.0f / (float)N_NODES;
    float4 hv = h4[idx];
    float4 ov = out4[idx];
    float m, var, sc;
    m = s.x * invN; var = sq.x * invN - m * m; sc = g.x * rsqrtf(var + BN_EPS);
    ov.x = hv.x + (ov.x - m) * sc + bt.x;
    m = s.y * invN; var = sq.y * invN - m * m; sc = g.y * rsqrtf(var + BN_EPS);
    ov.y = hv.y + (ov.y - m) * sc + bt.y;
    m = s.z * invN; var = sq.z * invN - m * m; sc = g.z * rsqrtf(var + BN_EPS);
    ov.z = hv.z + (ov.z - m) * sc + bt.z;
    m = s.w * invN; var = sq.w * invN - m * m; sc = g.w * rsqrtf(var + BN_EPS);
    ov.w = hv.w + (ov.w - m) * sc + bt.w;
    out4[idx] = ov;
}

// ---------------------------------------------------------------------------
extern "C" void kernel_launch(void* const* d_in, const int* in_sizes, int n_in,
                              void* d_out, int out_size, void* d_ws, size_t ws_size,
                              hipStream_t stream) {
    const float* h      = (const float*)d_in[0];
    const float* snorm  = (const float*)d_in[1];
    const float* Wself  = (const float*)d_in[2];
    const float* Wneigh = (const float*)d_in[3];
    const float* bias   = (const float*)d_in[4];
    const float* gamma  = (const float*)d_in[5];
    const float* beta   = (const float*)d_in[6];
    const int*   src    = (const int*)d_in[7];
    const int*   dst    = (const int*)d_in[8];
    float* out = (float*)d_out;

    // ws layout:
    // zeroed:   [ deg_i : N int ][ cursor : N int ][ sums : D f ][ sumsq : D f ]
    // unzeroed: [ row_start : N+1 ][ partials : 160 ][ esrc : E ]
    //           [ wfrag : 64KB ][ hb : 10.2MB ][ hnb : 10.2MB ]
    int*   deg_i     = (int*)d_ws;
    int*   cursor    = deg_i + N_NODES;
    float* sums      = (float*)(cursor + N_NODES);
    float* sumsq     = sums + D;
    int*   row_start = (int*)(sumsq + D);
    int*   partials  = row_start + (N_NODES + 1);
    int*   esrc      = partials + 160;
    size_t off       = (size_t)((char*)(esrc + N_EDGES) - (char*)d_ws);
    off = (off + 15) & ~(size_t)15;
    uint4* wfrag = (uint4*)((char*)d_ws + off);
    uint4* hb4   = wfrag + 4096;
    uint4* hnb4  = hb4 + N_NODES * (D / 8);

    size_t zero_bytes = (size_t)(2 * N_NODES + 2 * D) * sizeof(float);
    hipMemsetAsync(d_ws, 0, zero_bytes, stream);

    // 1a) degree histogram + h -> bf16 + W -> frag-major bf16
    hist_cvt_kernel<<<N_EDGES / 256, 256, 0, stream>>>(
        dst, deg_i, (const float4*)h, hb4, Wself, Wneigh, wfrag);
    // 1b) scan -> row_start (2 kernels)
    scan1_kernel<<<SCAN_BLOCKS, 256, 0, stream>>>(deg_i, partials);
    scan23_kernel<<<SCAN_BLOCKS, 256, 0, stream>>>(deg_i, partials, row_start);
    // 1c) bucket fill
    fill_kernel<<<N_EDGES / 256, 256, 0, stream>>>(src, dst, row_start, cursor, esrc);
    // 1d) gather + mean -> hnb (bf16), one wave per node
    gather_kernel<<<N_NODES / 4, 256, 0, stream>>>(hb4, row_start, esrc, hnb4);
    // 2) MFMA dual GEMM + relu + snorm + BN partials -> pre f32 (d_out)
    gemm_mfma_kernel<<<(N_NODES / 64) * 2, 256, 0, stream>>>(
        hb4, hnb4, wfrag, snorm, bias, out, sums, sumsq);
    // 3) finalize: residual + BN (in place on d_out)
    final_kernel<<<(N_NODES * D / 4) / 256, 256, 0, stream>>>(
        (const float4*)h, (const float4*)sums, (const float4*)sumsq,
        (const float4*)gamma, (const float4*)beta, (float4*)out);
}